// Round 15
// baseline (530.984 us; speedup 1.0000x reference)
//
#include <hip/hip_runtime.h>
#include <hip/hip_fp16.h>
#include <math.h>

#define CUTOFF_INV 0.2f
#define EPB_SHIFT 10
#define EPB 1024
#define HEPB 512            // edges per p2 block (half a p1 bin)
#define NBIN_MAX 1024
#define P1_CHUNK 4096
#define P1_THREADS 1024
#define P2_THREADS 512
#define SCAP 5120           // LDS sorted-record capacity per half-bin (mean ~4094)
#define GC_STRIDE 16        // gcount padding; [..+1] = overflow flag

typedef unsigned int uint;
typedef unsigned short ushort;

__device__ __forceinline__ float fcut(float r) {
    float p = r * CUTOFF_INV;
    float p2 = p * p;
    float p3 = p2 * p;
    return 1.0f + p3 * (-10.0f + p * (15.0f - 6.0f * p));
}

__device__ __forceinline__ void legendre_s(float ca, float& s0, float& s1, float& s2) {
    s0 = 0.5641895835477563f;
    s1 = 0.9772050238058398f * ca;
    s2 = 1.2615662610100802f * (1.5f * ca * ca - 0.5f);
}

// divide-free radial: v[l*3+n] = j_l(z_{l,n} * rik / cutoff) * fc(rik)
__device__ __forceinline__ void radial9(float rik, float* v) {
    float rr = rik * CUTOFF_INV;
    float inv = __builtin_amdgcn_rcpf(rr);
    inv = inv * (2.0f - rr * inv);
    float fcik = fcut(rik);

    const float Z0[3]  = {3.14159265358979324f, 6.28318530717958648f, 9.42477796076937972f};
    const float IZ0[3] = {1.0f / 3.14159265358979324f, 1.0f / 6.28318530717958648f, 1.0f / 9.42477796076937972f};
    const float Z1[3]  = {4.49340945790806150f, 7.72525183693865170f, 10.9041216594298970f};
    const float IZ1[3] = {1.0f / 4.49340945790806150f, 1.0f / 7.72525183693865170f, 1.0f / 10.9041216594298970f};
    const float Z2[3]  = {5.76345919689554900f, 9.09501133047736000f, 12.3229409705673230f};
    const float IZ2[3] = {1.0f / 5.76345919689554900f, 1.0f / 9.09501133047736000f, 1.0f / 12.3229409705673230f};

#pragma unroll
    for (int n = 0; n < 3; ++n) {
        float x = Z0[n] * rr;
        float invx = IZ0[n] * inv;
        v[n] = __sinf(x) * invx * fcik;
    }
#pragma unroll
    for (int n = 0; n < 3; ++n) {
        float x = Z1[n] * rr;
        float invx = IZ1[n] * inv;
        float s, c;
        __sincosf(x, &s, &c);
        v[3 + n] = (s * invx - c) * invx * fcik;
    }
#pragma unroll
    for (int n = 0; n < 3; ++n) {
        float x = Z2[n] * rr;
        float invx = IZ2[n] * inv;
        float s, c;
        __sincosf(x, &s, &c);
        float sx = s * invx;
        float j1 = (sx - c) * invx;
        v[6 + n] = (3.0f * invx * j1 - sx) * fcik;
    }
}

__device__ __forceinline__ float h2f(uint w) { return __half2float(__ushort_as_half((ushort)w)); }

// full per-record contribution c[9] (loads its own gate row)
__device__ __forceinline__ void contrib9(uint2 r, const uint* __restrict__ gate16h, float* c) {
    uint nk = r.y & 0xFFFFu;
    const uint* G = gate16h + ((size_t)nk << 3);
    uint4 q = *(const uint4*)G;
    uint q8 = G[4];
    float ca  = h2f(r.x >> 16);
    float rik = h2f(r.x & 0xFFFFu);
    float vr[9];
    radial9(rik, vr);
    float s0, s1, s2;
    legendre_s(ca, s0, s1, s2);
    c[0] = vr[0] * h2f(q.x & 0xFFFFu) * s0;
    c[1] = vr[1] * h2f(q.x >> 16) * s0;
    c[2] = vr[2] * h2f(q.y & 0xFFFFu) * s0;
    c[3] = vr[3] * h2f(q.y >> 16) * s1;
    c[4] = vr[4] * h2f(q.z & 0xFFFFu) * s1;
    c[5] = vr[5] * h2f(q.z >> 16) * s1;
    c[6] = vr[6] * h2f(q.w & 0xFFFFu) * s2;
    c[7] = vr[7] * h2f(q.w >> 16) * s2;
    c[8] = vr[8] * h2f(q8 & 0xFFFFu) * s2;
}

// ---------------- Stage 1: node gate -> packed f16 rows [N][8 uints] ----------------
__global__ void node_gate_h16_kernel(const float* __restrict__ nf,
                                     const float* __restrict__ W1,
                                     const float* __restrict__ b1,
                                     uint* __restrict__ gate16h, int N) {
    __shared__ float sW[64 * 9];
    __shared__ float sb[9];
    for (int i = threadIdx.x; i < 576; i += blockDim.x) sW[i] = W1[i];
    if (threadIdx.x < 9) sb[threadIdx.x] = b1[threadIdx.x];
    __syncthreads();
    int t = blockIdx.x * blockDim.x + threadIdx.x;
    if (t >= N) return;
    float acc[9];
#pragma unroll
    for (int d = 0; d < 9; ++d) acc[d] = sb[d];
    const float* row = nf + (size_t)t * 64;
#pragma unroll
    for (int f = 0; f < 64; ++f) {
        float x = row[f];
#pragma unroll
        for (int d = 0; d < 9; ++d) acc[d] += x * sW[f * 9 + d];
    }
    float g[9];
#pragma unroll
    for (int d = 0; d < 9; ++d) g[d] = 1.0f / (1.0f + __expf(-acc[d]));
    uint* o = gate16h + ((size_t)t << 3);
#pragma unroll
    for (int d = 0; d < 4; ++d) {
        uint lo = (uint)__half_as_ushort(__float2half_rn(g[2 * d]));
        uint hi = (uint)__half_as_ushort(__float2half_rn(g[2 * d + 1]));
        o[d] = lo | (hi << 16);
    }
    o[4] = (uint)__half_as_ushort(__float2half_rn(g[8]));
    o[5] = 0u; o[6] = 0u; o[7] = 0u;
}

// ---------------- Stage 1 (legacy): f32 gate [N,9] ----------------
__global__ void node_gate_f32_kernel(const float* __restrict__ nf,
                                     const float* __restrict__ W1,
                                     const float* __restrict__ b1,
                                     float* __restrict__ gate, int N) {
    __shared__ float sW[64 * 9];
    __shared__ float sb[9];
    for (int i = threadIdx.x; i < 576; i += blockDim.x) sW[i] = W1[i];
    if (threadIdx.x < 9) sb[threadIdx.x] = b1[threadIdx.x];
    __syncthreads();
    int t = blockIdx.x * blockDim.x + threadIdx.x;
    if (t >= N) return;
    float acc[9];
#pragma unroll
    for (int d = 0; d < 9; ++d) acc[d] = sb[d];
    const float* row = nf + (size_t)t * 64;
#pragma unroll
    for (int f = 0; f < 64; ++f) {
        float x = row[f];
#pragma unroll
        for (int d = 0; d < 9; ++d) acc[d] += x * sW[f * 9 + d];
    }
#pragma unroll
    for (int d = 0; d < 9; ++d)
        gate[(size_t)t * 9 + d] = 1.0f / (1.0f + __expf(-acc[d]));
}

// ---------------- Stage 2a: tab[e] = (f16(rik) << 16) | nk ----------------
__global__ void edge_tab_kernel(const float* __restrict__ dist,
                                const int* __restrict__ eidx,
                                uint* __restrict__ tab, int E) {
    int e = blockIdx.x * blockDim.x + threadIdx.x;
    if (e >= E) return;
    uint rh = (uint)__half_as_ushort(__float2half_rn(dist[e]));
    tab[e] = (rh << 16) | (uint)eidx[E + e];
}

// overflow fallback: accumulate one record straight into global mid
__device__ __forceinline__ void spill_rec(uint2 rec, int bin,
                                          const uint* __restrict__ gate16h,
                                          float* __restrict__ mid) {
    float c[9];
    contrib9(rec, gate16h, c);
    uint ijl = rec.y >> 16;
    float* dst = mid + ((size_t)bin * EPB + ijl) * 9;
#pragma unroll
    for (int d = 0; d < 9; ++d) atomicAdd(dst + d, c[d]);
}

// ---------------- Pass 1: block-local counting sort -> binned records ----------------
__global__ void __launch_bounds__(P1_THREADS) p1_sort_kernel(
        const float* __restrict__ ang,
        const int* __restrict__ tidx, // [2,T]
        const uint* __restrict__ tab, // [E]
        uint* __restrict__ gcount,    // [NBIN*GC_STRIDE]
        uint2* __restrict__ binbuf,   // [NBIN*BCAP]
        const uint* __restrict__ gate16h,
        float* __restrict__ mid,
        int T, int NBIN, int BCAP) {
    __shared__ uint hist[NBIN_MAX];
    __shared__ uint sc[NBIN_MAX];
    __shared__ uint gbase[NBIN_MAX];
    __shared__ uint lcur[NBIN_MAX];
    __shared__ uint2 sbuf[P1_CHUNK];
    __shared__ ushort sbin[P1_CHUNK];

    int t0 = blockIdx.x * P1_CHUNK;
    int m = T - t0;
    if (m <= 0) return;
    if (m > P1_CHUNK) m = P1_CHUNK;
    int tid = threadIdx.x;

    for (int i = tid; i < NBIN; i += blockDim.x) { hist[i] = 0; lcur[i] = 0; }
    __syncthreads();

    for (int i = tid; i < m; i += blockDim.x)
        atomicAdd(&hist[((uint)tidx[t0 + i]) >> EPB_SHIFT], 1u);
    __syncthreads();

    if (tid < NBIN) sc[tid] = hist[tid];
    __syncthreads();
    for (int off = 1; off < NBIN; off <<= 1) {
        uint v = 0;
        if (tid < NBIN) {
            v = sc[tid];
            if (tid >= off) v += sc[tid - off];
        }
        __syncthreads();
        if (tid < NBIN) sc[tid] = v;
        __syncthreads();
    }
    uint ex = 0, h = 0;
    if (tid < NBIN) {
        h = hist[tid];
        ex = sc[tid] - h;
    }
    __syncthreads();
    if (tid < NBIN) {
        sc[tid] = ex;
        gbase[tid] = h ? atomicAdd(&gcount[tid * GC_STRIDE], h) : 0u;
    }
    __syncthreads();

    for (int i = tid; i < m; i += blockDim.x) {
        int t = t0 + i;
        uint ij = (uint)tidx[t];
        uint ik = (uint)tidx[T + t];
        float ca = ang[t];
        uint te = tab[ik];
        uint bin = ij >> EPB_SHIFT;
        uint loc = atomicAdd(&lcur[bin], 1u);
        uint p = sc[bin] + loc;
        uint cah = (uint)__half_as_ushort(__float2half_rn(ca));
        sbuf[p] = make_uint2((cah << 16) | (te >> 16),
                             ((ij & (EPB - 1u)) << 16) | (te & 0xFFFFu));
        sbin[p] = (ushort)bin;
    }
    __syncthreads();

    for (int i = tid; i < m; i += blockDim.x) {
        uint bin = sbin[i];
        uint2 rec = sbuf[i];
        uint slot = gbase[bin] + ((uint)i - sc[bin]);
        if (slot < (uint)BCAP) {
            binbuf[(size_t)bin * BCAP + slot] = rec;
        } else {
            atomicOr(&gcount[bin * GC_STRIDE + 1], 1u);
            spill_rec(rec, bin, gate16h, mid);
        }
    }
}

// ---------------- Pass 2: in-LDS counting sort + BALANCED record-range accumulate ----------------
// Each thread handles a contiguous record range (K = ceil(total/512), forced odd), flushing
// its register accumulator to LDS umid (9 atomicAdds) only on edge change. Perfect lane
// balance vs thread=edge Poisson-max imbalance (~2x).
__global__ void __launch_bounds__(P2_THREADS) p2_sorted_kernel(
        const float* __restrict__ dist,
        const uint* __restrict__ gate16h, // [N,8]
        const uint* __restrict__ gcount,  // [NBIN*GC_STRIDE]
        const uint2* __restrict__ binbuf,
        const float* __restrict__ mid,    // [E,9] spill acc
        const float* __restrict__ attr,
        const float* __restrict__ Wm,
        const float* __restrict__ bm,
        const float* __restrict__ Wg,
        const float* __restrict__ bg,
        float* __restrict__ out,
        int E, int BCAP) {
    __shared__ uint2 srec[SCAP];          // 40 KB sorted records
    __shared__ float umid[HEPB * 9];      // 18 KB per-edge accumulator (separate; no aliasing)
    __shared__ uint cnt[HEPB];
    __shared__ uint off[HEPB];
    __shared__ float sWm[576], sWg[576], sbm[64], sbg[64];

    int tid = threadIdx.x;
    for (int i = tid; i < 576; i += P2_THREADS) { sWm[i] = Wm[i]; sWg[i] = Wg[i]; }
    if (tid < 64) { sbm[tid] = bm[tid]; sbg[tid] = bg[tid]; }
    cnt[tid] = 0;
    for (int i = tid; i < HEPB * 9; i += P2_THREADS) umid[i] = 0.0f;

    int bin = blockIdx.x >> 1;
    int hh  = blockIdx.x & 1;
    int ebase = (bin << EPB_SHIFT) + hh * HEPB;
    int ecnt = E - ebase; if (ecnt < 0) ecnt = 0; if (ecnt > HEPB) ecnt = HEPB;

    uint n = gcount[bin * GC_STRIDE];
    uint has_spill = gcount[bin * GC_STRIDE + 1];
    if (n > (uint)BCAP) n = (uint)BCAP;
    const uint2* rb = binbuf + (size_t)bin * BCAP;
    __syncthreads();

    // pass A: histogram of this half's records
    for (uint i = tid; i < n; i += P2_THREADS) {
        uint ijl = rb[i].y >> 16;
        if ((ijl >> 9) == (uint)hh) atomicAdd(&cnt[ijl & (HEPB - 1u)], 1u);
    }
    __syncthreads();
    uint myCnt = cnt[tid];
    off[tid] = myCnt;
    __syncthreads();
    for (int o = 1; o < HEPB; o <<= 1) {
        uint add = (tid >= o) ? off[tid - o] : 0u;
        __syncthreads();
        off[tid] += add;
        __syncthreads();
    }
    uint total = off[HEPB - 1];
    uint myBase = off[tid] - myCnt;
    __syncthreads();
    off[tid] = myBase;     // exclusive base per edge
    cnt[tid] = 0;          // scatter cursor
    __syncthreads();

    if (total <= (uint)SCAP) {
        // mode A: scatter into sorted LDS
        for (uint i = tid; i < n; i += P2_THREADS) {
            uint2 r = rb[i];
            uint ijl = r.y >> 16;
            if ((ijl >> 9) == (uint)hh) {
                uint e = ijl & (HEPB - 1u);
                uint p = off[e] + atomicAdd(&cnt[e], 1u);
                srec[p] = r;
            }
        }
        __syncthreads();
        // balanced accumulate: contiguous record range per thread, flush on edge change
        uint K = (total + P2_THREADS - 1) / P2_THREADS;
        K |= 1u;                               // odd stride: bank spread + balance
        uint jb = (uint)tid * K;
        uint je = jb + K; if (je > total) je = total;
        int cur = -1;
        float acc[9];
#pragma unroll
        for (int d = 0; d < 9; ++d) acc[d] = 0.0f;
        for (uint j = jb; j < je; ++j) {
            uint2 r = srec[j];
            int e = (int)((r.y >> 16) & (HEPB - 1u));
            if (e != cur) {
                if (cur >= 0) {
                    float* d0 = &umid[cur * 9];
#pragma unroll
                    for (int d = 0; d < 9; ++d) atomicAdd(d0 + d, acc[d]);
                }
                cur = e;
#pragma unroll
                for (int d = 0; d < 9; ++d) acc[d] = 0.0f;
            }
            float c[9];
            contrib9(r, gate16h, c);
#pragma unroll
            for (int d = 0; d < 9; ++d) acc[d] += c[d];
        }
        if (cur >= 0) {
            float* d0 = &umid[cur * 9];
#pragma unroll
            for (int d = 0; d < 9; ++d) atomicAdd(d0 + d, acc[d]);
        }
        __syncthreads();
    } else {
        // mode B (rare fat half-bin): atomic accumulate straight into umid
        for (uint i = tid; i < n; i += P2_THREADS) {
            uint2 r = rb[i];
            uint ijl = r.y >> 16;
            if ((ijl >> 9) == (uint)hh) {
                uint e = ijl & (HEPB - 1u);
                float c[9];
                contrib9(r, gate16h, c);
                float* d0 = &umid[e * 9];
#pragma unroll
                for (int d = 0; d < 9; ++d) atomicAdd(d0 + d, c[d]);
            }
        }
        __syncthreads();
    }

    // merge fc(rij) (+ spill) in umid
    if (tid < ecnt) {
        int e = ebase + tid;
        float fc = fcut(dist[e]);
        float* ls = &umid[tid * 9];
        if (has_spill) {
            const float* mg = mid + (size_t)e * 9;
#pragma unroll
            for (int d = 0; d < 9; ++d) ls[d] = fc * (ls[d] + mg[d]);
        } else {
#pragma unroll
            for (int d = 0; d < 9; ++d) ls[d] *= fc;
        }
    }
    __syncthreads();

    // GatedMLP epilogue: wave per edge, lane = feature
    int wid  = tid >> 6;
    int lane = tid & 63;
    for (int el = wid; el < ecnt; el += (P2_THREADS >> 6)) {
        int e = ebase + el;
        const float* ls = &umid[el * 9];
        float am = sbm[lane], ag = sbg[lane];
#pragma unroll
        for (int d = 0; d < 9; ++d) {
            float ud = ls[d];
            am += ud * sWm[d * 64 + lane];
            ag += ud * sWg[d * 64 + lane];
        }
        float hsw = am / (1.0f + __expf(-am));
        float gt  = 1.0f / (1.0f + __expf(-ag));
        size_t ofs = (size_t)e * 64 + lane;
        out[ofs] = attr[ofs] + hsw * gt;
    }
}

// ---------------- Legacy fallback (round-1 path) ----------------
__global__ void triplet_kernel(const float* __restrict__ dist,
                               const float* __restrict__ ang,
                               const int* __restrict__ tidx,
                               const int* __restrict__ eidx,
                               const float* __restrict__ gate,
                               float* __restrict__ mid,
                               int T, int E) {
    int t = blockIdx.x * blockDim.x + threadIdx.x;
    if (t >= T) return;
    int ij = tidx[t];
    int ik = tidx[T + t];
    float ca  = ang[t];
    float rij = dist[ij];
    float rik = dist[ik];
    float frij = fcut(rij);
    int nk = eidx[E + ik];
    const float* g = gate + (size_t)nk * 9;
    float vr[9];
    radial9(rik, vr);
    float s0, s1, s2;
    legendre_s(ca, s0, s1, s2);
    s0 *= frij; s1 *= frij; s2 *= frij;
    float* dst = mid + (size_t)ij * 9;
    atomicAdd(dst + 0, vr[0] * s0 * g[0]);
    atomicAdd(dst + 1, vr[1] * s0 * g[1]);
    atomicAdd(dst + 2, vr[2] * s0 * g[2]);
    atomicAdd(dst + 3, vr[3] * s1 * g[3]);
    atomicAdd(dst + 4, vr[4] * s1 * g[4]);
    atomicAdd(dst + 5, vr[5] * s1 * g[5]);
    atomicAdd(dst + 6, vr[6] * s2 * g[6]);
    atomicAdd(dst + 7, vr[7] * s2 * g[7]);
    atomicAdd(dst + 8, vr[8] * s2 * g[8]);
}

__global__ void edge_kernel(const float* __restrict__ mid,
                            const float* __restrict__ attr,
                            const float* __restrict__ Wm, const float* __restrict__ bm,
                            const float* __restrict__ Wg, const float* __restrict__ bg,
                            float* __restrict__ out, int E) {
    __shared__ float sWm[9 * 64], sWg[9 * 64], sbm[64], sbg[64];
    for (int i = threadIdx.x; i < 576; i += blockDim.x) {
        sWm[i] = Wm[i];
        sWg[i] = Wg[i];
    }
    if (threadIdx.x < 64) {
        sbm[threadIdx.x] = bm[threadIdx.x];
        sbg[threadIdx.x] = bg[threadIdx.x];
    }
    __syncthreads();
    int wid  = threadIdx.x >> 6;
    int lane = threadIdx.x & 63;
    int e = blockIdx.x * (blockDim.x >> 6) + wid;
    if (e >= E) return;
    const float* u = mid + (size_t)e * 9;
    float am = sbm[lane], ag = sbg[lane];
#pragma unroll
    for (int d = 0; d < 9; ++d) {
        float ud = u[d];
        am += ud * sWm[d * 64 + lane];
        ag += ud * sWg[d * 64 + lane];
    }
    float h  = am / (1.0f + __expf(-am));
    float gt = 1.0f / (1.0f + __expf(-ag));
    size_t off = (size_t)e * 64 + lane;
    out[off] = attr[off] + h * gt;
}

extern "C" void kernel_launch(void* const* d_in, const int* in_sizes, int n_in,
                              void* d_out, int out_size, void* d_ws, size_t ws_size,
                              hipStream_t stream) {
    const float* dist = (const float*)d_in[0];
    const float* ang  = (const float*)d_in[1];
    const float* nf   = (const float*)d_in[2];
    const float* attr = (const float*)d_in[3];
    const float* W1   = (const float*)d_in[4];
    const float* b1   = (const float*)d_in[5];
    const float* Wm   = (const float*)d_in[6];
    const float* bm   = (const float*)d_in[7];
    const float* Wg   = (const float*)d_in[8];
    const float* bg   = (const float*)d_in[9];
    const int* tidx   = (const int*)d_in[10];
    const int* eidx   = (const int*)d_in[11];

    int E = in_sizes[0];
    int T = in_sizes[1];
    int N = in_sizes[2] / 64;

    int NBIN = (E + EPB - 1) >> EPB_SHIFT;
    int mean = T / (NBIN > 0 ? NBIN : 1);

    int bcap1 = ((mean + mean / 8 + 512) + 15) & ~15;
    int bcap2 = ((mean + mean / 32 + 256) + 15) & ~15;

    size_t o_gate  = 0;
    size_t o_tab   = o_gate + (size_t)N * 8;
    size_t o_mid   = o_tab + (size_t)E;
    size_t o_gcnt  = o_mid + (size_t)E * 9;
    size_t o_bb    = (o_gcnt + (size_t)NBIN * GC_STRIDE + 15) & ~(size_t)15;
    auto need = [&](int cap) { return (o_bb + (size_t)NBIN * cap * 2) * 4; };

    int BCAP = 0;
    if (ws_size >= need(bcap1)) BCAP = bcap1;
    else if (ws_size >= need(bcap2)) BCAP = bcap2;

    bool newpath = (E <= (1 << 20)) && (N <= 65535) && (NBIN <= NBIN_MAX)
                   && (NBIN <= P1_THREADS) && (BCAP > 0);

    float* wsf = (float*)d_ws;

    if (newpath) {
        uint*  gate16h = (uint*)(wsf + o_gate);
        uint*  tab     = (uint*)(wsf + o_tab);
        float* mid     = wsf + o_mid;
        uint*  gcount  = (uint*)(wsf + o_gcnt);
        uint2* binbuf  = (uint2*)(wsf + o_bb);

        hipMemsetAsync(gcount, 0, (size_t)NBIN * GC_STRIDE * sizeof(uint), stream);
        hipMemsetAsync(mid, 0, (size_t)E * 9 * sizeof(float), stream);
        node_gate_h16_kernel<<<(N + 255) / 256, 256, 0, stream>>>(nf, W1, b1, gate16h, N);
        edge_tab_kernel<<<(E + 255) / 256, 256, 0, stream>>>(dist, eidx, tab, E);

        int p1grid = (T + P1_CHUNK - 1) / P1_CHUNK;
        p1_sort_kernel<<<p1grid, P1_THREADS, 0, stream>>>(ang, tidx, tab, gcount, binbuf,
                                                          gate16h, mid, T, NBIN, BCAP);
        p2_sorted_kernel<<<NBIN * 2, P2_THREADS, 0, stream>>>(dist, gate16h, gcount, binbuf, mid,
                                                              attr, Wm, bm, Wg, bg,
                                                              (float*)d_out, E, BCAP);
    } else {
        float* gate = wsf;
        float* mid = gate + (((size_t)N * 9 + 15) & ~(size_t)15);
        hipMemsetAsync(mid, 0, (size_t)E * 9 * sizeof(float), stream);
        node_gate_f32_kernel<<<(N + 255) / 256, 256, 0, stream>>>(nf, W1, b1, gate, N);
        triplet_kernel<<<(T + 255) / 256, 256, 0, stream>>>(dist, ang, tidx, eidx, gate, mid, T, E);
        edge_kernel<<<(E + 3) / 4, 256, 0, stream>>>(mid, attr, Wm, bm, Wg, bg, (float*)d_out, E);
    }
}

// Round 16
// 477.278 us; speedup vs baseline: 1.1125x; 1.1125x over previous
//
#include <hip/hip_runtime.h>
#include <hip/hip_fp16.h>
#include <math.h>

#define CUTOFF_INV 0.2f
#define EPB_SHIFT 9
#define EPB 512             // edges per bin == edges per p2 block
#define NBIN_MAX 2048
#define P1_CHUNK 4096
#define P1_THREADS 1024
#define P2_THREADS 512
#define SCAP 4608           // LDS sorted-record capacity per bin (mean ~3906, ~11 sigma)
#define GC_STRIDE 16        // gcount padding; [..+1] = overflow flag

typedef unsigned int uint;
typedef unsigned short ushort;

__device__ __forceinline__ float fcut(float r) {
    float p = r * CUTOFF_INV;
    float p2 = p * p;
    float p3 = p2 * p;
    return 1.0f + p3 * (-10.0f + p * (15.0f - 6.0f * p));
}

__device__ __forceinline__ void legendre_s(float ca, float& s0, float& s1, float& s2) {
    s0 = 0.5641895835477563f;
    s1 = 0.9772050238058398f * ca;
    s2 = 1.2615662610100802f * (1.5f * ca * ca - 0.5f);
}

// divide-free radial: v[l*3+n] = j_l(z_{l,n} * rik / cutoff) * fc(rik)
__device__ __forceinline__ void radial9(float rik, float* v) {
    float rr = rik * CUTOFF_INV;
    float inv = __builtin_amdgcn_rcpf(rr);
    inv = inv * (2.0f - rr * inv);
    float fcik = fcut(rik);

    const float Z0[3]  = {3.14159265358979324f, 6.28318530717958648f, 9.42477796076937972f};
    const float IZ0[3] = {1.0f / 3.14159265358979324f, 1.0f / 6.28318530717958648f, 1.0f / 9.42477796076937972f};
    const float Z1[3]  = {4.49340945790806150f, 7.72525183693865170f, 10.9041216594298970f};
    const float IZ1[3] = {1.0f / 4.49340945790806150f, 1.0f / 7.72525183693865170f, 1.0f / 10.9041216594298970f};
    const float Z2[3]  = {5.76345919689554900f, 9.09501133047736000f, 12.3229409705673230f};
    const float IZ2[3] = {1.0f / 5.76345919689554900f, 1.0f / 9.09501133047736000f, 1.0f / 12.3229409705673230f};

#pragma unroll
    for (int n = 0; n < 3; ++n) {
        float x = Z0[n] * rr;
        float invx = IZ0[n] * inv;
        v[n] = __sinf(x) * invx * fcik;
    }
#pragma unroll
    for (int n = 0; n < 3; ++n) {
        float x = Z1[n] * rr;
        float invx = IZ1[n] * inv;
        float s, c;
        __sincosf(x, &s, &c);
        v[3 + n] = (s * invx - c) * invx * fcik;
    }
#pragma unroll
    for (int n = 0; n < 3; ++n) {
        float x = Z2[n] * rr;
        float invx = IZ2[n] * inv;
        float s, c;
        __sincosf(x, &s, &c);
        float sx = s * invx;
        float j1 = (sx - c) * invx;
        v[6 + n] = (3.0f * invx * j1 - sx) * fcik;
    }
}

__device__ __forceinline__ float h2f(uint w) { return __half2float(__ushort_as_half((ushort)w)); }

// full per-record contribution c[9] (loads its own gate row)
__device__ __forceinline__ void contrib9(uint2 r, const uint* __restrict__ gate16h, float* c) {
    uint nk = r.y & 0xFFFFu;
    const uint* G = gate16h + ((size_t)nk << 3);
    uint4 q = *(const uint4*)G;
    uint q8 = G[4];
    float ca  = h2f(r.x >> 16);
    float rik = h2f(r.x & 0xFFFFu);
    float vr[9];
    radial9(rik, vr);
    float s0, s1, s2;
    legendre_s(ca, s0, s1, s2);
    c[0] = vr[0] * h2f(q.x & 0xFFFFu) * s0;
    c[1] = vr[1] * h2f(q.x >> 16) * s0;
    c[2] = vr[2] * h2f(q.y & 0xFFFFu) * s0;
    c[3] = vr[3] * h2f(q.y >> 16) * s1;
    c[4] = vr[4] * h2f(q.z & 0xFFFFu) * s1;
    c[5] = vr[5] * h2f(q.z >> 16) * s1;
    c[6] = vr[6] * h2f(q.w & 0xFFFFu) * s2;
    c[7] = vr[7] * h2f(q.w >> 16) * s2;
    c[8] = vr[8] * h2f(q8 & 0xFFFFu) * s2;
}

// ---------------- Stage 1: node gate -> packed f16 rows [N][8 uints] ----------------
__global__ void node_gate_h16_kernel(const float* __restrict__ nf,
                                     const float* __restrict__ W1,
                                     const float* __restrict__ b1,
                                     uint* __restrict__ gate16h, int N) {
    __shared__ float sW[64 * 9];
    __shared__ float sb[9];
    for (int i = threadIdx.x; i < 576; i += blockDim.x) sW[i] = W1[i];
    if (threadIdx.x < 9) sb[threadIdx.x] = b1[threadIdx.x];
    __syncthreads();
    int t = blockIdx.x * blockDim.x + threadIdx.x;
    if (t >= N) return;
    float acc[9];
#pragma unroll
    for (int d = 0; d < 9; ++d) acc[d] = sb[d];
    const float* row = nf + (size_t)t * 64;
#pragma unroll
    for (int f = 0; f < 64; ++f) {
        float x = row[f];
#pragma unroll
        for (int d = 0; d < 9; ++d) acc[d] += x * sW[f * 9 + d];
    }
    float g[9];
#pragma unroll
    for (int d = 0; d < 9; ++d) g[d] = 1.0f / (1.0f + __expf(-acc[d]));
    uint* o = gate16h + ((size_t)t << 3);
#pragma unroll
    for (int d = 0; d < 4; ++d) {
        uint lo = (uint)__half_as_ushort(__float2half_rn(g[2 * d]));
        uint hi = (uint)__half_as_ushort(__float2half_rn(g[2 * d + 1]));
        o[d] = lo | (hi << 16);
    }
    o[4] = (uint)__half_as_ushort(__float2half_rn(g[8]));
    o[5] = 0u; o[6] = 0u; o[7] = 0u;
}

// ---------------- Stage 1 (legacy): f32 gate [N,9] ----------------
__global__ void node_gate_f32_kernel(const float* __restrict__ nf,
                                     const float* __restrict__ W1,
                                     const float* __restrict__ b1,
                                     float* __restrict__ gate, int N) {
    __shared__ float sW[64 * 9];
    __shared__ float sb[9];
    for (int i = threadIdx.x; i < 576; i += blockDim.x) sW[i] = W1[i];
    if (threadIdx.x < 9) sb[threadIdx.x] = b1[threadIdx.x];
    __syncthreads();
    int t = blockIdx.x * blockDim.x + threadIdx.x;
    if (t >= N) return;
    float acc[9];
#pragma unroll
    for (int d = 0; d < 9; ++d) acc[d] = sb[d];
    const float* row = nf + (size_t)t * 64;
#pragma unroll
    for (int f = 0; f < 64; ++f) {
        float x = row[f];
#pragma unroll
        for (int d = 0; d < 9; ++d) acc[d] += x * sW[f * 9 + d];
    }
#pragma unroll
    for (int d = 0; d < 9; ++d)
        gate[(size_t)t * 9 + d] = 1.0f / (1.0f + __expf(-acc[d]));
}

// ---------------- Stage 2a: tab[e] = (f16(rik) << 16) | nk ----------------
__global__ void edge_tab_kernel(const float* __restrict__ dist,
                                const int* __restrict__ eidx,
                                uint* __restrict__ tab, int E) {
    int e = blockIdx.x * blockDim.x + threadIdx.x;
    if (e >= E) return;
    uint rh = (uint)__half_as_ushort(__float2half_rn(dist[e]));
    tab[e] = (rh << 16) | (uint)eidx[E + e];
}

// overflow fallback: accumulate one record straight into global mid
__device__ __forceinline__ void spill_rec(uint2 rec, int bin,
                                          const uint* __restrict__ gate16h,
                                          float* __restrict__ mid) {
    float c[9];
    contrib9(rec, gate16h, c);
    uint ijl = (rec.y >> 16) & (EPB - 1u);
    float* dst = mid + ((size_t)bin * EPB + ijl) * 9;
#pragma unroll
    for (int d = 0; d < 9; ++d) atomicAdd(dst + d, c[d]);
}

// ---------------- Pass 1: block-local counting sort -> 2048 native bins ----------------
// Pair-based scan: thread owns bins 2*tid and 2*tid+1. LDS compacted: hist reused as
// delta = gbase - localBase; scatter cursor lcur starts at localBase.
__global__ void __launch_bounds__(P1_THREADS) p1_sort_kernel(
        const float* __restrict__ ang,
        const int* __restrict__ tidx, // [2,T]
        const uint* __restrict__ tab, // [E]
        uint* __restrict__ gcount,    // [NBIN*GC_STRIDE]
        uint2* __restrict__ binbuf,   // [NBIN*BCAP]
        const uint* __restrict__ gate16h,
        float* __restrict__ mid,
        int T, int NBIN, int BCAP) {
    __shared__ int  delta[NBIN_MAX];      // 8 KB; first used as hist
    __shared__ uint lcur[NBIN_MAX];       // 8 KB
    __shared__ uint pairs[P1_THREADS];    // 4 KB
    __shared__ uint2 sbuf[P1_CHUNK];      // 32 KB
    __shared__ ushort sbin[P1_CHUNK];     // 8 KB
    uint* hist = (uint*)delta;

    int t0 = blockIdx.x * P1_CHUNK;
    int m = T - t0;
    if (m <= 0) return;
    if (m > P1_CHUNK) m = P1_CHUNK;
    int tid = threadIdx.x;

    for (int i = tid; i < NBIN; i += blockDim.x) hist[i] = 0u;
    __syncthreads();

    for (int i = tid; i < m; i += blockDim.x)
        atomicAdd(&hist[((uint)tidx[t0 + i]) >> EPB_SHIFT], 1u);
    __syncthreads();

    int b0 = 2 * tid, b1 = 2 * tid + 1;
    uint h0 = (b0 < NBIN) ? hist[b0] : 0u;
    uint h1 = (b1 < NBIN) ? hist[b1] : 0u;
    pairs[tid] = h0 + h1;
    __syncthreads();
    for (int off = 1; off < P1_THREADS; off <<= 1) {
        uint v = pairs[tid];
        if (tid >= off) v += pairs[tid - off];
        __syncthreads();
        pairs[tid] = v;
        __syncthreads();
    }
    uint exPair = pairs[tid] - (h0 + h1);
    uint ex0 = exPair, ex1 = exPair + h0;
    __syncthreads();   // all hist reads done before delta overwrite
    if (b0 < NBIN) {
        lcur[b0] = ex0;
        uint gb = h0 ? atomicAdd(&gcount[b0 * GC_STRIDE], h0) : 0u;
        delta[b0] = (int)gb - (int)ex0;
    }
    if (b1 < NBIN) {
        lcur[b1] = ex1;
        uint gb = h1 ? atomicAdd(&gcount[b1 * GC_STRIDE], h1) : 0u;
        delta[b1] = (int)gb - (int)ex1;
    }
    __syncthreads();

    // pass B: build records, place sorted by bin (cursor starts at local base)
    for (int i = tid; i < m; i += blockDim.x) {
        int t = t0 + i;
        uint ij = (uint)tidx[t];
        uint ik = (uint)tidx[T + t];
        float ca = ang[t];
        uint te = tab[ik];
        uint bin = ij >> EPB_SHIFT;
        uint p = atomicAdd(&lcur[bin], 1u);
        uint cah = (uint)__half_as_ushort(__float2half_rn(ca));
        sbuf[p] = make_uint2((cah << 16) | (te >> 16),
                             ((ij & (EPB - 1u)) << 16) | (te & 0xFFFFu));
        sbin[p] = (ushort)bin;
    }
    __syncthreads();

    // pass C: coalesced writeout of sorted runs
    for (int i = tid; i < m; i += blockDim.x) {
        uint bin = sbin[i];
        uint2 rec = sbuf[i];
        int slot = i + delta[bin];     // = gbase + (i - localBase), >= 0
        if ((uint)slot < (uint)BCAP) {
            binbuf[(size_t)bin * BCAP + slot] = rec;
        } else {
            atomicOr(&gcount[bin * GC_STRIDE + 1], 1u);
            spill_rec(rec, (int)bin, gate16h, mid);
        }
    }
}

// ---------------- Pass 2: one bin per block; in-LDS sort + register accumulate ----------------
// Block reads ONLY its own records (no hh predicate, no redundant stream). 45 KB LDS -> 3 blocks/CU.
__global__ void __launch_bounds__(P2_THREADS) p2_sorted_kernel(
        const float* __restrict__ dist,
        const uint* __restrict__ gate16h, // [N,8]
        const uint* __restrict__ gcount,  // [NBIN*GC_STRIDE]
        const uint2* __restrict__ binbuf,
        const float* __restrict__ mid,    // [E,9] spill acc
        const float* __restrict__ attr,
        const float* __restrict__ Wm,
        const float* __restrict__ bm,
        const float* __restrict__ Wg,
        const float* __restrict__ bg,
        float* __restrict__ out,
        int E, int BCAP) {
    __shared__ uint2 srec[SCAP];          // 36 KB; aliased as umid after use
    __shared__ uint cnt[EPB];             // 2 KB
    __shared__ uint off[EPB];             // 2 KB
    __shared__ float sWm[576], sWg[576], sbm[64], sbg[64];
    float* umid = (float*)srec;           // [EPB*9] aliased (18 KB < 36 KB)

    int tid = threadIdx.x;
    for (int i = tid; i < 576; i += P2_THREADS) { sWm[i] = Wm[i]; sWg[i] = Wg[i]; }
    if (tid < 64) { sbm[tid] = bm[tid]; sbg[tid] = bg[tid]; }
    cnt[tid] = 0;

    int bin = blockIdx.x;
    int ebase = bin << EPB_SHIFT;
    int ecnt = E - ebase; if (ecnt < 0) ecnt = 0; if (ecnt > EPB) ecnt = EPB;

    uint n = gcount[bin * GC_STRIDE];
    uint has_spill = gcount[bin * GC_STRIDE + 1];
    if (n > (uint)BCAP) n = (uint)BCAP;
    const uint2* rb = binbuf + (size_t)bin * BCAP;
    __syncthreads();

    // pass A: histogram (every record is ours)
    for (uint i = tid; i < n; i += P2_THREADS)
        atomicAdd(&cnt[(rb[i].y >> 16) & (EPB - 1u)], 1u);
    __syncthreads();
    uint myCnt = cnt[tid];
    off[tid] = myCnt;
    __syncthreads();
    for (int o = 1; o < EPB; o <<= 1) {
        uint add = (tid >= o) ? off[tid - o] : 0u;
        __syncthreads();
        off[tid] += add;
        __syncthreads();
    }
    uint myBase = off[tid] - myCnt;
    __syncthreads();
    off[tid] = myBase;     // exclusive base per edge
    cnt[tid] = 0;          // scatter cursor
    __syncthreads();

    float acc[9];
#pragma unroll
    for (int d = 0; d < 9; ++d) acc[d] = 0.0f;

    if (n <= (uint)SCAP) {
        // mode A: scatter into sorted LDS
        for (uint i = tid; i < n; i += P2_THREADS) {
            uint2 r = rb[i];
            uint e = (r.y >> 16) & (EPB - 1u);
            uint p = off[e] + atomicAdd(&cnt[e], 1u);
            srec[p] = r;
        }
        __syncthreads();
        // thread = edge: serial register accumulation, zero atomics
        for (uint j = 0; j < myCnt; ++j) {
            float c[9];
            contrib9(srec[myBase + j], gate16h, c);
#pragma unroll
            for (int d = 0; d < 9; ++d) acc[d] += c[d];
        }
        __syncthreads();   // all srec reads done before umid aliasing writes
    } else {
        // mode B (rare fat bin): atomic accumulate into umid region
        for (int i = tid; i < EPB * 9; i += P2_THREADS) umid[i] = 0.0f;
        __syncthreads();
        for (uint i = tid; i < n; i += P2_THREADS) {
            uint2 r = rb[i];
            uint e = (r.y >> 16) & (EPB - 1u);
            float c[9];
            contrib9(r, gate16h, c);
            float* d0 = &umid[e * 9];
#pragma unroll
            for (int d = 0; d < 9; ++d) atomicAdd(d0 + d, c[d]);
        }
        __syncthreads();
        if (tid < ecnt) {
#pragma unroll
            for (int d = 0; d < 9; ++d) acc[d] = umid[tid * 9 + d];
        }
        __syncthreads();
    }

    // merge fc(rij) (+ spill) and stage umid for the epilogue
    if (tid < ecnt) {
        int e = ebase + tid;
        float fc = fcut(dist[e]);
        if (has_spill) {
            const float* mg = mid + (size_t)e * 9;
#pragma unroll
            for (int d = 0; d < 9; ++d) acc[d] = fc * (acc[d] + mg[d]);
        } else {
#pragma unroll
            for (int d = 0; d < 9; ++d) acc[d] *= fc;
        }
#pragma unroll
        for (int d = 0; d < 9; ++d) umid[tid * 9 + d] = acc[d];
    }
    __syncthreads();

    // GatedMLP epilogue: wave per edge, lane = feature
    int wid  = tid >> 6;
    int lane = tid & 63;
    for (int el = wid; el < ecnt; el += (P2_THREADS >> 6)) {
        int e = ebase + el;
        const float* ls = &umid[el * 9];
        float am = sbm[lane], ag = sbg[lane];
#pragma unroll
        for (int d = 0; d < 9; ++d) {
            float ud = ls[d];
            am += ud * sWm[d * 64 + lane];
            ag += ud * sWg[d * 64 + lane];
        }
        float hsw = am / (1.0f + __expf(-am));
        float gt  = 1.0f / (1.0f + __expf(-ag));
        size_t ofs = (size_t)e * 64 + lane;
        out[ofs] = attr[ofs] + hsw * gt;
    }
}

// ---------------- Legacy fallback (round-1 path) ----------------
__global__ void triplet_kernel(const float* __restrict__ dist,
                               const float* __restrict__ ang,
                               const int* __restrict__ tidx,
                               const int* __restrict__ eidx,
                               const float* __restrict__ gate,
                               float* __restrict__ mid,
                               int T, int E) {
    int t = blockIdx.x * blockDim.x + threadIdx.x;
    if (t >= T) return;
    int ij = tidx[t];
    int ik = tidx[T + t];
    float ca  = ang[t];
    float rij = dist[ij];
    float rik = dist[ik];
    float frij = fcut(rij);
    int nk = eidx[E + ik];
    const float* g = gate + (size_t)nk * 9;
    float vr[9];
    radial9(rik, vr);
    float s0, s1, s2;
    legendre_s(ca, s0, s1, s2);
    s0 *= frij; s1 *= frij; s2 *= frij;
    float* dst = mid + (size_t)ij * 9;
    atomicAdd(dst + 0, vr[0] * s0 * g[0]);
    atomicAdd(dst + 1, vr[1] * s0 * g[1]);
    atomicAdd(dst + 2, vr[2] * s0 * g[2]);
    atomicAdd(dst + 3, vr[3] * s1 * g[3]);
    atomicAdd(dst + 4, vr[4] * s1 * g[4]);
    atomicAdd(dst + 5, vr[5] * s1 * g[5]);
    atomicAdd(dst + 6, vr[6] * s2 * g[6]);
    atomicAdd(dst + 7, vr[7] * s2 * g[7]);
    atomicAdd(dst + 8, vr[8] * s2 * g[8]);
}

__global__ void edge_kernel(const float* __restrict__ mid,
                            const float* __restrict__ attr,
                            const float* __restrict__ Wm, const float* __restrict__ bm,
                            const float* __restrict__ Wg, const float* __restrict__ bg,
                            float* __restrict__ out, int E) {
    __shared__ float sWm[9 * 64], sWg[9 * 64], sbm[64], sbg[64];
    for (int i = threadIdx.x; i < 576; i += blockDim.x) {
        sWm[i] = Wm[i];
        sWg[i] = Wg[i];
    }
    if (threadIdx.x < 64) {
        sbm[threadIdx.x] = bm[threadIdx.x];
        sbg[threadIdx.x] = bg[threadIdx.x];
    }
    __syncthreads();
    int wid  = threadIdx.x >> 6;
    int lane = threadIdx.x & 63;
    int e = blockIdx.x * (blockDim.x >> 6) + wid;
    if (e >= E) return;
    const float* u = mid + (size_t)e * 9;
    float am = sbm[lane], ag = sbg[lane];
#pragma unroll
    for (int d = 0; d < 9; ++d) {
        float ud = u[d];
        am += ud * sWm[d * 64 + lane];
        ag += ud * sWg[d * 64 + lane];
    }
    float h  = am / (1.0f + __expf(-am));
    float gt = 1.0f / (1.0f + __expf(-ag));
    size_t off = (size_t)e * 64 + lane;
    out[off] = attr[off] + h * gt;
}

extern "C" void kernel_launch(void* const* d_in, const int* in_sizes, int n_in,
                              void* d_out, int out_size, void* d_ws, size_t ws_size,
                              hipStream_t stream) {
    const float* dist = (const float*)d_in[0];
    const float* ang  = (const float*)d_in[1];
    const float* nf   = (const float*)d_in[2];
    const float* attr = (const float*)d_in[3];
    const float* W1   = (const float*)d_in[4];
    const float* b1   = (const float*)d_in[5];
    const float* Wm   = (const float*)d_in[6];
    const float* bm   = (const float*)d_in[7];
    const float* Wg   = (const float*)d_in[8];
    const float* bg   = (const float*)d_in[9];
    const int* tidx   = (const int*)d_in[10];
    const int* eidx   = (const int*)d_in[11];

    int E = in_sizes[0];
    int T = in_sizes[1];
    int N = in_sizes[2] / 64;

    int NBIN = (E + EPB - 1) >> EPB_SHIFT;
    int mean = T / (NBIN > 0 ? NBIN : 1);

    int bcap1 = ((mean + mean / 8 + 512) + 15) & ~15;
    int bcap2 = ((mean + mean / 32 + 256) + 15) & ~15;

    size_t o_gate  = 0;
    size_t o_tab   = o_gate + (size_t)N * 8;
    size_t o_mid   = o_tab + (size_t)E;
    size_t o_gcnt  = o_mid + (size_t)E * 9;
    size_t o_bb    = (o_gcnt + (size_t)NBIN * GC_STRIDE + 15) & ~(size_t)15;
    auto need = [&](int cap) { return (o_bb + (size_t)NBIN * cap * 2) * 4; };

    int BCAP = 0;
    if (ws_size >= need(bcap1)) BCAP = bcap1;
    else if (ws_size >= need(bcap2)) BCAP = bcap2;

    bool newpath = (E <= (1 << 20)) && (N <= 65535) && (NBIN <= NBIN_MAX)
                   && (NBIN <= 2 * P1_THREADS) && (BCAP > 0);

    float* wsf = (float*)d_ws;

    if (newpath) {
        uint*  gate16h = (uint*)(wsf + o_gate);
        uint*  tab     = (uint*)(wsf + o_tab);
        float* mid     = wsf + o_mid;
        uint*  gcount  = (uint*)(wsf + o_gcnt);
        uint2* binbuf  = (uint2*)(wsf + o_bb);

        hipMemsetAsync(gcount, 0, (size_t)NBIN * GC_STRIDE * sizeof(uint), stream);
        hipMemsetAsync(mid, 0, (size_t)E * 9 * sizeof(float), stream);
        node_gate_h16_kernel<<<(N + 255) / 256, 256, 0, stream>>>(nf, W1, b1, gate16h, N);
        edge_tab_kernel<<<(E + 255) / 256, 256, 0, stream>>>(dist, eidx, tab, E);

        int p1grid = (T + P1_CHUNK - 1) / P1_CHUNK;
        p1_sort_kernel<<<p1grid, P1_THREADS, 0, stream>>>(ang, tidx, tab, gcount, binbuf,
                                                          gate16h, mid, T, NBIN, BCAP);
        p2_sorted_kernel<<<NBIN, P2_THREADS, 0, stream>>>(dist, gate16h, gcount, binbuf, mid,
                                                          attr, Wm, bm, Wg, bg,
                                                          (float*)d_out, E, BCAP);
    } else {
        float* gate = wsf;
        float* mid = gate + (((size_t)N * 9 + 15) & ~(size_t)15);
        hipMemsetAsync(mid, 0, (size_t)E * 9 * sizeof(float), stream);
        node_gate_f32_kernel<<<(N + 255) / 256, 256, 0, stream>>>(nf, W1, b1, gate, N);
        triplet_kernel<<<(T + 255) / 256, 256, 0, stream>>>(dist, ang, tidx, eidx, gate, mid, T, E);
        edge_kernel<<<(E + 3) / 4, 256, 0, stream>>>(mid, attr, Wm, bm, Wg, bg, (float*)d_out, E);
    }
}

// Round 17
// 439.784 us; speedup vs baseline: 1.2074x; 1.0853x over previous
//
#include <hip/hip_runtime.h>
#include <hip/hip_fp16.h>
#include <math.h>

#define CUTOFF_INV 0.2f
#define EPB_SHIFT 9
#define EPB 512             // edges per bin == edges per p2 block
#define NBIN_MAX 2048
#define P1_CHUNK 8192
#define P1_THREADS 1024
#define P2_THREADS 512
#define SCAP 4608           // LDS sorted-record capacity per bin (mean ~3906, ~11 sigma)
#define GC_STRIDE 16        // gcount padding; [..+1] = overflow flag

typedef unsigned int uint;
typedef unsigned short ushort;

__device__ __forceinline__ float fcut(float r) {
    float p = r * CUTOFF_INV;
    float p2 = p * p;
    float p3 = p2 * p;
    return 1.0f + p3 * (-10.0f + p * (15.0f - 6.0f * p));
}

__device__ __forceinline__ void legendre_s(float ca, float& s0, float& s1, float& s2) {
    s0 = 0.5641895835477563f;
    s1 = 0.9772050238058398f * ca;
    s2 = 1.2615662610100802f * (1.5f * ca * ca - 0.5f);
}

// divide-free radial: v[l*3+n] = j_l(z_{l,n} * rik / cutoff) * fc(rik)
__device__ __forceinline__ void radial9(float rik, float* v) {
    float rr = rik * CUTOFF_INV;
    float inv = __builtin_amdgcn_rcpf(rr);
    inv = inv * (2.0f - rr * inv);
    float fcik = fcut(rik);

    const float Z0[3]  = {3.14159265358979324f, 6.28318530717958648f, 9.42477796076937972f};
    const float IZ0[3] = {1.0f / 3.14159265358979324f, 1.0f / 6.28318530717958648f, 1.0f / 9.42477796076937972f};
    const float Z1[3]  = {4.49340945790806150f, 7.72525183693865170f, 10.9041216594298970f};
    const float IZ1[3] = {1.0f / 4.49340945790806150f, 1.0f / 7.72525183693865170f, 1.0f / 10.9041216594298970f};
    const float Z2[3]  = {5.76345919689554900f, 9.09501133047736000f, 12.3229409705673230f};
    const float IZ2[3] = {1.0f / 5.76345919689554900f, 1.0f / 9.09501133047736000f, 1.0f / 12.3229409705673230f};

#pragma unroll
    for (int n = 0; n < 3; ++n) {
        float x = Z0[n] * rr;
        float invx = IZ0[n] * inv;
        v[n] = __sinf(x) * invx * fcik;
    }
#pragma unroll
    for (int n = 0; n < 3; ++n) {
        float x = Z1[n] * rr;
        float invx = IZ1[n] * inv;
        float s, c;
        __sincosf(x, &s, &c);
        v[3 + n] = (s * invx - c) * invx * fcik;
    }
#pragma unroll
    for (int n = 0; n < 3; ++n) {
        float x = Z2[n] * rr;
        float invx = IZ2[n] * inv;
        float s, c;
        __sincosf(x, &s, &c);
        float sx = s * invx;
        float j1 = (sx - c) * invx;
        v[6 + n] = (3.0f * invx * j1 - sx) * fcik;
    }
}

__device__ __forceinline__ float h2f(uint w) { return __half2float(__ushort_as_half((ushort)w)); }

// full per-record contribution c[9] (loads its own gate row)
__device__ __forceinline__ void contrib9(uint2 r, const uint* __restrict__ gate16h, float* c) {
    uint nk = r.y & 0xFFFFu;
    const uint* G = gate16h + ((size_t)nk << 3);
    uint4 q = *(const uint4*)G;
    uint q8 = G[4];
    float ca  = h2f(r.x >> 16);
    float rik = h2f(r.x & 0xFFFFu);
    float vr[9];
    radial9(rik, vr);
    float s0, s1, s2;
    legendre_s(ca, s0, s1, s2);
    c[0] = vr[0] * h2f(q.x & 0xFFFFu) * s0;
    c[1] = vr[1] * h2f(q.x >> 16) * s0;
    c[2] = vr[2] * h2f(q.y & 0xFFFFu) * s0;
    c[3] = vr[3] * h2f(q.y >> 16) * s1;
    c[4] = vr[4] * h2f(q.z & 0xFFFFu) * s1;
    c[5] = vr[5] * h2f(q.z >> 16) * s1;
    c[6] = vr[6] * h2f(q.w & 0xFFFFu) * s2;
    c[7] = vr[7] * h2f(q.w >> 16) * s2;
    c[8] = vr[8] * h2f(q8 & 0xFFFFu) * s2;
}

// ---------------- Stage 1: node gate -> packed f16 rows [N][8 uints] ----------------
__global__ void node_gate_h16_kernel(const float* __restrict__ nf,
                                     const float* __restrict__ W1,
                                     const float* __restrict__ b1,
                                     uint* __restrict__ gate16h, int N) {
    __shared__ float sW[64 * 9];
    __shared__ float sb[9];
    for (int i = threadIdx.x; i < 576; i += blockDim.x) sW[i] = W1[i];
    if (threadIdx.x < 9) sb[threadIdx.x] = b1[threadIdx.x];
    __syncthreads();
    int t = blockIdx.x * blockDim.x + threadIdx.x;
    if (t >= N) return;
    float acc[9];
#pragma unroll
    for (int d = 0; d < 9; ++d) acc[d] = sb[d];
    const float* row = nf + (size_t)t * 64;
#pragma unroll
    for (int f = 0; f < 64; ++f) {
        float x = row[f];
#pragma unroll
        for (int d = 0; d < 9; ++d) acc[d] += x * sW[f * 9 + d];
    }
    float g[9];
#pragma unroll
    for (int d = 0; d < 9; ++d) g[d] = 1.0f / (1.0f + __expf(-acc[d]));
    uint* o = gate16h + ((size_t)t << 3);
#pragma unroll
    for (int d = 0; d < 4; ++d) {
        uint lo = (uint)__half_as_ushort(__float2half_rn(g[2 * d]));
        uint hi = (uint)__half_as_ushort(__float2half_rn(g[2 * d + 1]));
        o[d] = lo | (hi << 16);
    }
    o[4] = (uint)__half_as_ushort(__float2half_rn(g[8]));
    o[5] = 0u; o[6] = 0u; o[7] = 0u;
}

// ---------------- Stage 1 (legacy): f32 gate [N,9] ----------------
__global__ void node_gate_f32_kernel(const float* __restrict__ nf,
                                     const float* __restrict__ W1,
                                     const float* __restrict__ b1,
                                     float* __restrict__ gate, int N) {
    __shared__ float sW[64 * 9];
    __shared__ float sb[9];
    for (int i = threadIdx.x; i < 576; i += blockDim.x) sW[i] = W1[i];
    if (threadIdx.x < 9) sb[threadIdx.x] = b1[threadIdx.x];
    __syncthreads();
    int t = blockIdx.x * blockDim.x + threadIdx.x;
    if (t >= N) return;
    float acc[9];
#pragma unroll
    for (int d = 0; d < 9; ++d) acc[d] = sb[d];
    const float* row = nf + (size_t)t * 64;
#pragma unroll
    for (int f = 0; f < 64; ++f) {
        float x = row[f];
#pragma unroll
        for (int d = 0; d < 9; ++d) acc[d] += x * sW[f * 9 + d];
    }
#pragma unroll
    for (int d = 0; d < 9; ++d)
        gate[(size_t)t * 9 + d] = 1.0f / (1.0f + __expf(-acc[d]));
}

// ---------------- Stage 2a: tab[e] = (f16(rik) << 16) | nk ----------------
__global__ void edge_tab_kernel(const float* __restrict__ dist,
                                const int* __restrict__ eidx,
                                uint* __restrict__ tab, int E) {
    int e = blockIdx.x * blockDim.x + threadIdx.x;
    if (e >= E) return;
    uint rh = (uint)__half_as_ushort(__float2half_rn(dist[e]));
    tab[e] = (rh << 16) | (uint)eidx[E + e];
}

// overflow fallback: accumulate one record straight into global mid
__device__ __forceinline__ void spill_rec(uint2 rec, int bin,
                                          const uint* __restrict__ gate16h,
                                          float* __restrict__ mid) {
    float c[9];
    contrib9(rec, gate16h, c);
    uint ijl = (rec.y >> 16) & (EPB - 1u);
    float* dst = mid + ((size_t)bin * EPB + ijl) * 9;
#pragma unroll
    for (int d = 0; d < 9; ++d) atomicAdd(dst + d, c[d]);
}

// ---------------- Pass 1: block-local counting sort -> 2048 native bins ----------------
// CHUNK=8192 (runs of ~4 records -> 2x less partial-line write amplification).
// Pair-based scan via wave shuffles (3 barriers instead of 20).
__global__ void __launch_bounds__(P1_THREADS) p1_sort_kernel(
        const float* __restrict__ ang,
        const int* __restrict__ tidx, // [2,T]
        const uint* __restrict__ tab, // [E]
        uint* __restrict__ gcount,    // [NBIN*GC_STRIDE]
        uint2* __restrict__ binbuf,   // [NBIN*BCAP]
        const uint* __restrict__ gate16h,
        float* __restrict__ mid,
        int T, int NBIN, int BCAP) {
    __shared__ int  delta[NBIN_MAX];      // 8 KB; first used as hist
    __shared__ uint lcur[NBIN_MAX];       // 8 KB
    __shared__ uint wsum[16];
    __shared__ uint2 sbuf[P1_CHUNK];      // 64 KB
    __shared__ ushort sbin[P1_CHUNK];     // 16 KB
    uint* hist = (uint*)delta;

    int t0 = blockIdx.x * P1_CHUNK;
    int m = T - t0;
    if (m <= 0) return;
    if (m > P1_CHUNK) m = P1_CHUNK;
    int tid = threadIdx.x;

    for (int i = tid; i < NBIN; i += blockDim.x) hist[i] = 0u;
    __syncthreads();

    for (int i = tid; i < m; i += blockDim.x)
        atomicAdd(&hist[((uint)tidx[t0 + i]) >> EPB_SHIFT], 1u);
    __syncthreads();

    // pair scan over 2048 bins with wave shuffles
    int b0 = 2 * tid, b1 = 2 * tid + 1;
    uint h0 = (b0 < NBIN) ? hist[b0] : 0u;
    uint h1 = (b1 < NBIN) ? hist[b1] : 0u;
    uint v = h0 + h1;
    uint lane = (uint)tid & 63u;
    uint wv = (uint)tid >> 6;
    uint sv = v;
#pragma unroll
    for (int o = 1; o < 64; o <<= 1) {
        uint u = __shfl_up(sv, o);
        if ((int)lane >= o) sv += u;
    }
    if (lane == 63u) wsum[wv] = sv;
    __syncthreads();
    if (tid == 0) {
        uint s = 0;
        for (int w = 0; w < 16; ++w) { uint x = wsum[w]; wsum[w] = s; s += x; }
    }
    __syncthreads();
    uint incl = sv + wsum[wv];
    uint exPair = incl - v;
    uint ex0 = exPair, ex1 = exPair + h0;
    __syncthreads();   // all hist reads done before delta overwrite
    if (b0 < NBIN) {
        lcur[b0] = ex0;
        uint gb = h0 ? atomicAdd(&gcount[b0 * GC_STRIDE], h0) : 0u;
        delta[b0] = (int)gb - (int)ex0;
    }
    if (b1 < NBIN) {
        lcur[b1] = ex1;
        uint gb = h1 ? atomicAdd(&gcount[b1 * GC_STRIDE], h1) : 0u;
        delta[b1] = (int)gb - (int)ex1;
    }
    __syncthreads();

    // pass B: build records, place sorted by bin (cursor starts at local base)
    for (int i = tid; i < m; i += blockDim.x) {
        int t = t0 + i;
        uint ij = (uint)tidx[t];
        uint ik = (uint)tidx[T + t];
        float ca = ang[t];
        uint te = tab[ik];
        uint bin = ij >> EPB_SHIFT;
        uint p = atomicAdd(&lcur[bin], 1u);
        uint cah = (uint)__half_as_ushort(__float2half_rn(ca));
        sbuf[p] = make_uint2((cah << 16) | (te >> 16),
                             ((ij & (EPB - 1u)) << 16) | (te & 0xFFFFu));
        sbin[p] = (ushort)bin;
    }
    __syncthreads();

    // pass C: coalesced writeout of sorted runs
    for (int i = tid; i < m; i += blockDim.x) {
        uint bin = sbin[i];
        uint2 rec = sbuf[i];
        int slot = i + delta[bin];     // = gbase + (i - localBase), >= 0
        if ((uint)slot < (uint)BCAP) {
            binbuf[(size_t)bin * BCAP + slot] = rec;
        } else {
            atomicOr(&gcount[bin * GC_STRIDE + 1], 1u);
            spill_rec(rec, (int)bin, gate16h, mid);
        }
    }
}

// ---------------- Pass 2: one bin per block; in-LDS sort + register accumulate ----------------
__global__ void __launch_bounds__(P2_THREADS) p2_sorted_kernel(
        const float* __restrict__ dist,
        const uint* __restrict__ gate16h, // [N,8]
        const uint* __restrict__ gcount,  // [NBIN*GC_STRIDE]
        const uint2* __restrict__ binbuf,
        const float* __restrict__ mid,    // [E,9] spill acc
        const float* __restrict__ attr,
        const float* __restrict__ Wm,
        const float* __restrict__ bm,
        const float* __restrict__ Wg,
        const float* __restrict__ bg,
        float* __restrict__ out,
        int E, int BCAP) {
    __shared__ uint2 srec[SCAP];          // 36 KB; aliased as umid after use
    __shared__ uint cnt[EPB];             // 2 KB
    __shared__ uint off[EPB];             // 2 KB
    __shared__ uint wsum[8];
    __shared__ float sWm[576], sWg[576], sbm[64], sbg[64];
    float* umid = (float*)srec;           // [EPB*9] aliased (18 KB < 36 KB)

    int tid = threadIdx.x;
    for (int i = tid; i < 576; i += P2_THREADS) { sWm[i] = Wm[i]; sWg[i] = Wg[i]; }
    if (tid < 64) { sbm[tid] = bm[tid]; sbg[tid] = bg[tid]; }
    cnt[tid] = 0;

    int bin = blockIdx.x;
    int ebase = bin << EPB_SHIFT;
    int ecnt = E - ebase; if (ecnt < 0) ecnt = 0; if (ecnt > EPB) ecnt = EPB;

    uint n = gcount[bin * GC_STRIDE];
    uint has_spill = gcount[bin * GC_STRIDE + 1];
    if (n > (uint)BCAP) n = (uint)BCAP;
    const uint2* rb = binbuf + (size_t)bin * BCAP;
    __syncthreads();

    // pass A: histogram (every record is ours)
    for (uint i = tid; i < n; i += P2_THREADS)
        atomicAdd(&cnt[(rb[i].y >> 16) & (EPB - 1u)], 1u);
    __syncthreads();
    uint myCnt = cnt[tid];
    // wave-shuffle scan over 512 elements (3 barriers)
    uint lane = (uint)tid & 63u;
    uint wv = (uint)tid >> 6;
    uint sv = myCnt;
#pragma unroll
    for (int o = 1; o < 64; o <<= 1) {
        uint u = __shfl_up(sv, o);
        if ((int)lane >= o) sv += u;
    }
    if (lane == 63u) wsum[wv] = sv;
    __syncthreads();
    if (tid == 0) {
        uint s = 0;
        for (int w = 0; w < 8; ++w) { uint x = wsum[w]; wsum[w] = s; s += x; }
    }
    __syncthreads();
    uint myBase = sv + wsum[wv] - myCnt;
    off[tid] = myBase;     // exclusive base per edge
    cnt[tid] = 0;          // scatter cursor
    __syncthreads();

    float acc[9];
#pragma unroll
    for (int d = 0; d < 9; ++d) acc[d] = 0.0f;

    if (n <= (uint)SCAP) {
        // mode A: scatter into sorted LDS
        for (uint i = tid; i < n; i += P2_THREADS) {
            uint2 r = rb[i];
            uint e = (r.y >> 16) & (EPB - 1u);
            uint p = off[e] + atomicAdd(&cnt[e], 1u);
            srec[p] = r;
        }
        __syncthreads();
        // thread = edge: serial register accumulation, zero atomics
        for (uint j = 0; j < myCnt; ++j) {
            float c[9];
            contrib9(srec[myBase + j], gate16h, c);
#pragma unroll
            for (int d = 0; d < 9; ++d) acc[d] += c[d];
        }
        __syncthreads();   // all srec reads done before umid aliasing writes
    } else {
        // mode B (rare fat bin): atomic accumulate into umid region
        for (int i = tid; i < EPB * 9; i += P2_THREADS) umid[i] = 0.0f;
        __syncthreads();
        for (uint i = tid; i < n; i += P2_THREADS) {
            uint2 r = rb[i];
            uint e = (r.y >> 16) & (EPB - 1u);
            float c[9];
            contrib9(r, gate16h, c);
            float* d0 = &umid[e * 9];
#pragma unroll
            for (int d = 0; d < 9; ++d) atomicAdd(d0 + d, c[d]);
        }
        __syncthreads();
        if (tid < ecnt) {
#pragma unroll
            for (int d = 0; d < 9; ++d) acc[d] = umid[tid * 9 + d];
        }
        __syncthreads();
    }

    // merge fc(rij) (+ spill) and stage umid for the epilogue
    if (tid < ecnt) {
        int e = ebase + tid;
        float fc = fcut(dist[e]);
        if (has_spill) {
            const float* mg = mid + (size_t)e * 9;
#pragma unroll
            for (int d = 0; d < 9; ++d) acc[d] = fc * (acc[d] + mg[d]);
        } else {
#pragma unroll
            for (int d = 0; d < 9; ++d) acc[d] *= fc;
        }
#pragma unroll
        for (int d = 0; d < 9; ++d) umid[tid * 9 + d] = acc[d];
    }
    __syncthreads();

    // GatedMLP epilogue: wave per edge, lane = feature
    int wid  = tid >> 6;
    int lane2 = tid & 63;
    for (int el = wid; el < ecnt; el += (P2_THREADS >> 6)) {
        int e = ebase + el;
        const float* ls = &umid[el * 9];
        float am = sbm[lane2], ag = sbg[lane2];
#pragma unroll
        for (int d = 0; d < 9; ++d) {
            float ud = ls[d];
            am += ud * sWm[d * 64 + lane2];
            ag += ud * sWg[d * 64 + lane2];
        }
        float hsw = am / (1.0f + __expf(-am));
        float gt  = 1.0f / (1.0f + __expf(-ag));
        size_t ofs = (size_t)e * 64 + lane2;
        out[ofs] = attr[ofs] + hsw * gt;
    }
}

// ---------------- Legacy fallback (round-1 path) ----------------
__global__ void triplet_kernel(const float* __restrict__ dist,
                               const float* __restrict__ ang,
                               const int* __restrict__ tidx,
                               const int* __restrict__ eidx,
                               const float* __restrict__ gate,
                               float* __restrict__ mid,
                               int T, int E) {
    int t = blockIdx.x * blockDim.x + threadIdx.x;
    if (t >= T) return;
    int ij = tidx[t];
    int ik = tidx[T + t];
    float ca  = ang[t];
    float rij = dist[ij];
    float rik = dist[ik];
    float frij = fcut(rij);
    int nk = eidx[E + ik];
    const float* g = gate + (size_t)nk * 9;
    float vr[9];
    radial9(rik, vr);
    float s0, s1, s2;
    legendre_s(ca, s0, s1, s2);
    s0 *= frij; s1 *= frij; s2 *= frij;
    float* dst = mid + (size_t)ij * 9;
    atomicAdd(dst + 0, vr[0] * s0 * g[0]);
    atomicAdd(dst + 1, vr[1] * s0 * g[1]);
    atomicAdd(dst + 2, vr[2] * s0 * g[2]);
    atomicAdd(dst + 3, vr[3] * s1 * g[3]);
    atomicAdd(dst + 4, vr[4] * s1 * g[4]);
    atomicAdd(dst + 5, vr[5] * s1 * g[5]);
    atomicAdd(dst + 6, vr[6] * s2 * g[6]);
    atomicAdd(dst + 7, vr[7] * s2 * g[7]);
    atomicAdd(dst + 8, vr[8] * s2 * g[8]);
}

__global__ void edge_kernel(const float* __restrict__ mid,
                            const float* __restrict__ attr,
                            const float* __restrict__ Wm, const float* __restrict__ bm,
                            const float* __restrict__ Wg, const float* __restrict__ bg,
                            float* __restrict__ out, int E) {
    __shared__ float sWm[9 * 64], sWg[9 * 64], sbm[64], sbg[64];
    for (int i = threadIdx.x; i < 576; i += blockDim.x) {
        sWm[i] = Wm[i];
        sWg[i] = Wg[i];
    }
    if (threadIdx.x < 64) {
        sbm[threadIdx.x] = bm[threadIdx.x];
        sbg[threadIdx.x] = bg[threadIdx.x];
    }
    __syncthreads();
    int wid  = threadIdx.x >> 6;
    int lane = threadIdx.x & 63;
    int e = blockIdx.x * (blockDim.x >> 6) + wid;
    if (e >= E) return;
    const float* u = mid + (size_t)e * 9;
    float am = sbm[lane], ag = sbg[lane];
#pragma unroll
    for (int d = 0; d < 9; ++d) {
        float ud = u[d];
        am += ud * sWm[d * 64 + lane];
        ag += ud * sWg[d * 64 + lane];
    }
    float h  = am / (1.0f + __expf(-am));
    float gt = 1.0f / (1.0f + __expf(-ag));
    size_t off = (size_t)e * 64 + lane;
    out[off] = attr[off] + h * gt;
}

extern "C" void kernel_launch(void* const* d_in, const int* in_sizes, int n_in,
                              void* d_out, int out_size, void* d_ws, size_t ws_size,
                              hipStream_t stream) {
    const float* dist = (const float*)d_in[0];
    const float* ang  = (const float*)d_in[1];
    const float* nf   = (const float*)d_in[2];
    const float* attr = (const float*)d_in[3];
    const float* W1   = (const float*)d_in[4];
    const float* b1   = (const float*)d_in[5];
    const float* Wm   = (const float*)d_in[6];
    const float* bm   = (const float*)d_in[7];
    const float* Wg   = (const float*)d_in[8];
    const float* bg   = (const float*)d_in[9];
    const int* tidx   = (const int*)d_in[10];
    const int* eidx   = (const int*)d_in[11];

    int E = in_sizes[0];
    int T = in_sizes[1];
    int N = in_sizes[2] / 64;

    int NBIN = (E + EPB - 1) >> EPB_SHIFT;
    int mean = T / (NBIN > 0 ? NBIN : 1);

    int bcap1 = ((mean + mean / 8 + 512) + 15) & ~15;
    int bcap2 = ((mean + mean / 32 + 256) + 15) & ~15;

    size_t o_gate  = 0;
    size_t o_tab   = o_gate + (size_t)N * 8;
    size_t o_mid   = o_tab + (size_t)E;
    size_t o_gcnt  = o_mid + (size_t)E * 9;
    size_t o_bb    = (o_gcnt + (size_t)NBIN * GC_STRIDE + 15) & ~(size_t)15;
    auto need = [&](int cap) { return (o_bb + (size_t)NBIN * cap * 2) * 4; };

    int BCAP = 0;
    if (ws_size >= need(bcap1)) BCAP = bcap1;
    else if (ws_size >= need(bcap2)) BCAP = bcap2;

    bool newpath = (E <= (1 << 20)) && (N <= 65535) && (NBIN <= NBIN_MAX)
                   && (NBIN <= 2 * P1_THREADS) && (BCAP > 0);

    float* wsf = (float*)d_ws;

    if (newpath) {
        uint*  gate16h = (uint*)(wsf + o_gate);
        uint*  tab     = (uint*)(wsf + o_tab);
        float* mid     = wsf + o_mid;
        uint*  gcount  = (uint*)(wsf + o_gcnt);
        uint2* binbuf  = (uint2*)(wsf + o_bb);

        hipMemsetAsync(gcount, 0, (size_t)NBIN * GC_STRIDE * sizeof(uint), stream);
        hipMemsetAsync(mid, 0, (size_t)E * 9 * sizeof(float), stream);
        node_gate_h16_kernel<<<(N + 255) / 256, 256, 0, stream>>>(nf, W1, b1, gate16h, N);
        edge_tab_kernel<<<(E + 255) / 256, 256, 0, stream>>>(dist, eidx, tab, E);

        int p1grid = (T + P1_CHUNK - 1) / P1_CHUNK;
        p1_sort_kernel<<<p1grid, P1_THREADS, 0, stream>>>(ang, tidx, tab, gcount, binbuf,
                                                          gate16h, mid, T, NBIN, BCAP);
        p2_sorted_kernel<<<NBIN, P2_THREADS, 0, stream>>>(dist, gate16h, gcount, binbuf, mid,
                                                          attr, Wm, bm, Wg, bg,
                                                          (float*)d_out, E, BCAP);
    } else {
        float* gate = wsf;
        float* mid = gate + (((size_t)N * 9 + 15) & ~(size_t)15);
        hipMemsetAsync(mid, 0, (size_t)E * 9 * sizeof(float), stream);
        node_gate_f32_kernel<<<(N + 255) / 256, 256, 0, stream>>>(nf, W1, b1, gate, N);
        triplet_kernel<<<(T + 255) / 256, 256, 0, stream>>>(dist, ang, tidx, eidx, gate, mid, T, E);
        edge_kernel<<<(E + 3) / 4, 256, 0, stream>>>(mid, attr, Wm, bm, Wg, bg, (float*)d_out, E);
    }
}

// Round 18
// 427.578 us; speedup vs baseline: 1.2418x; 1.0285x over previous
//
#include <hip/hip_runtime.h>
#include <hip/hip_fp16.h>
#include <math.h>

#define CUTOFF_INV 0.2f
#define EPB_SHIFT 9
#define EPB 512             // edges per bin == edges per p2 block
#define NBIN_MAX 2048
#define P1_CHUNK 8192
#define P1_THREADS 1024
#define P2_THREADS 1024     // 2 threads per edge
#define SCAP 4608           // LDS sorted-record capacity per bin (mean ~3906, ~11 sigma)
#define GC_STRIDE 16        // gcount padding; [..+1] = overflow flag

typedef unsigned int uint;
typedef unsigned short ushort;

__device__ __forceinline__ float fcut(float r) {
    float p = r * CUTOFF_INV;
    float p2 = p * p;
    float p3 = p2 * p;
    return 1.0f + p3 * (-10.0f + p * (15.0f - 6.0f * p));
}

__device__ __forceinline__ void legendre_s(float ca, float& s0, float& s1, float& s2) {
    s0 = 0.5641895835477563f;
    s1 = 0.9772050238058398f * ca;
    s2 = 1.2615662610100802f * (1.5f * ca * ca - 0.5f);
}

// divide-free radial: v[l*3+n] = j_l(z_{l,n} * rik / cutoff) * fc(rik)
__device__ __forceinline__ void radial9(float rik, float* v) {
    float rr = rik * CUTOFF_INV;
    float inv = __builtin_amdgcn_rcpf(rr);
    inv = inv * (2.0f - rr * inv);
    float fcik = fcut(rik);

    const float Z0[3]  = {3.14159265358979324f, 6.28318530717958648f, 9.42477796076937972f};
    const float IZ0[3] = {1.0f / 3.14159265358979324f, 1.0f / 6.28318530717958648f, 1.0f / 9.42477796076937972f};
    const float Z1[3]  = {4.49340945790806150f, 7.72525183693865170f, 10.9041216594298970f};
    const float IZ1[3] = {1.0f / 4.49340945790806150f, 1.0f / 7.72525183693865170f, 1.0f / 10.9041216594298970f};
    const float Z2[3]  = {5.76345919689554900f, 9.09501133047736000f, 12.3229409705673230f};
    const float IZ2[3] = {1.0f / 5.76345919689554900f, 1.0f / 9.09501133047736000f, 1.0f / 12.3229409705673230f};

#pragma unroll
    for (int n = 0; n < 3; ++n) {
        float x = Z0[n] * rr;
        float invx = IZ0[n] * inv;
        v[n] = __sinf(x) * invx * fcik;
    }
#pragma unroll
    for (int n = 0; n < 3; ++n) {
        float x = Z1[n] * rr;
        float invx = IZ1[n] * inv;
        float s, c;
        __sincosf(x, &s, &c);
        v[3 + n] = (s * invx - c) * invx * fcik;
    }
#pragma unroll
    for (int n = 0; n < 3; ++n) {
        float x = Z2[n] * rr;
        float invx = IZ2[n] * inv;
        float s, c;
        __sincosf(x, &s, &c);
        float sx = s * invx;
        float j1 = (sx - c) * invx;
        v[6 + n] = (3.0f * invx * j1 - sx) * fcik;
    }
}

__device__ __forceinline__ float h2f(uint w) { return __half2float(__ushort_as_half((ushort)w)); }

// full per-record contribution c[9] (loads its own gate row)
__device__ __forceinline__ void contrib9(uint2 r, const uint* __restrict__ gate16h, float* c) {
    uint nk = r.y & 0xFFFFu;
    const uint* G = gate16h + ((size_t)nk << 3);
    uint4 q = *(const uint4*)G;
    uint q8 = G[4];
    float ca  = h2f(r.x >> 16);
    float rik = h2f(r.x & 0xFFFFu);
    float vr[9];
    radial9(rik, vr);
    float s0, s1, s2;
    legendre_s(ca, s0, s1, s2);
    c[0] = vr[0] * h2f(q.x & 0xFFFFu) * s0;
    c[1] = vr[1] * h2f(q.x >> 16) * s0;
    c[2] = vr[2] * h2f(q.y & 0xFFFFu) * s0;
    c[3] = vr[3] * h2f(q.y >> 16) * s1;
    c[4] = vr[4] * h2f(q.z & 0xFFFFu) * s1;
    c[5] = vr[5] * h2f(q.z >> 16) * s1;
    c[6] = vr[6] * h2f(q.w & 0xFFFFu) * s2;
    c[7] = vr[7] * h2f(q.w >> 16) * s2;
    c[8] = vr[8] * h2f(q8 & 0xFFFFu) * s2;
}

// ---------------- Stage 1: node gate -> packed f16 rows [N][8 uints] ----------------
__global__ void node_gate_h16_kernel(const float* __restrict__ nf,
                                     const float* __restrict__ W1,
                                     const float* __restrict__ b1,
                                     uint* __restrict__ gate16h, int N) {
    __shared__ float sW[64 * 9];
    __shared__ float sb[9];
    for (int i = threadIdx.x; i < 576; i += blockDim.x) sW[i] = W1[i];
    if (threadIdx.x < 9) sb[threadIdx.x] = b1[threadIdx.x];
    __syncthreads();
    int t = blockIdx.x * blockDim.x + threadIdx.x;
    if (t >= N) return;
    float acc[9];
#pragma unroll
    for (int d = 0; d < 9; ++d) acc[d] = sb[d];
    const float* row = nf + (size_t)t * 64;
#pragma unroll
    for (int f = 0; f < 64; ++f) {
        float x = row[f];
#pragma unroll
        for (int d = 0; d < 9; ++d) acc[d] += x * sW[f * 9 + d];
    }
    float g[9];
#pragma unroll
    for (int d = 0; d < 9; ++d) g[d] = 1.0f / (1.0f + __expf(-acc[d]));
    uint* o = gate16h + ((size_t)t << 3);
#pragma unroll
    for (int d = 0; d < 4; ++d) {
        uint lo = (uint)__half_as_ushort(__float2half_rn(g[2 * d]));
        uint hi = (uint)__half_as_ushort(__float2half_rn(g[2 * d + 1]));
        o[d] = lo | (hi << 16);
    }
    o[4] = (uint)__half_as_ushort(__float2half_rn(g[8]));
    o[5] = 0u; o[6] = 0u; o[7] = 0u;
}

// ---------------- Stage 1 (legacy): f32 gate [N,9] ----------------
__global__ void node_gate_f32_kernel(const float* __restrict__ nf,
                                     const float* __restrict__ W1,
                                     const float* __restrict__ b1,
                                     float* __restrict__ gate, int N) {
    __shared__ float sW[64 * 9];
    __shared__ float sb[9];
    for (int i = threadIdx.x; i < 576; i += blockDim.x) sW[i] = W1[i];
    if (threadIdx.x < 9) sb[threadIdx.x] = b1[threadIdx.x];
    __syncthreads();
    int t = blockIdx.x * blockDim.x + threadIdx.x;
    if (t >= N) return;
    float acc[9];
#pragma unroll
    for (int d = 0; d < 9; ++d) acc[d] = sb[d];
    const float* row = nf + (size_t)t * 64;
#pragma unroll
    for (int f = 0; f < 64; ++f) {
        float x = row[f];
#pragma unroll
        for (int d = 0; d < 9; ++d) acc[d] += x * sW[f * 9 + d];
    }
#pragma unroll
    for (int d = 0; d < 9; ++d)
        gate[(size_t)t * 9 + d] = 1.0f / (1.0f + __expf(-acc[d]));
}

// ---------------- Stage 2a: tab[e] = (f16(rik) << 16) | nk ----------------
__global__ void edge_tab_kernel(const float* __restrict__ dist,
                                const int* __restrict__ eidx,
                                uint* __restrict__ tab, int E) {
    int e = blockIdx.x * blockDim.x + threadIdx.x;
    if (e >= E) return;
    uint rh = (uint)__half_as_ushort(__float2half_rn(dist[e]));
    tab[e] = (rh << 16) | (uint)eidx[E + e];
}

// overflow fallback: accumulate one record straight into global mid
__device__ __forceinline__ void spill_rec(uint2 rec, int bin,
                                          const uint* __restrict__ gate16h,
                                          float* __restrict__ mid) {
    float c[9];
    contrib9(rec, gate16h, c);
    uint ijl = (rec.y >> 16) & (EPB - 1u);
    float* dst = mid + ((size_t)bin * EPB + ijl) * 9;
#pragma unroll
    for (int d = 0; d < 9; ++d) atomicAdd(dst + d, c[d]);
}

// ---------------- Pass 1: block-local counting sort -> 2048 native bins ----------------
__global__ void __launch_bounds__(P1_THREADS) p1_sort_kernel(
        const float* __restrict__ ang,
        const int* __restrict__ tidx, // [2,T]
        const uint* __restrict__ tab, // [E]
        uint* __restrict__ gcount,    // [NBIN*GC_STRIDE]
        uint2* __restrict__ binbuf,   // [NBIN*BCAP]
        const uint* __restrict__ gate16h,
        float* __restrict__ mid,
        int T, int NBIN, int BCAP) {
    __shared__ int  delta[NBIN_MAX];      // 8 KB; first used as hist
    __shared__ uint lcur[NBIN_MAX];       // 8 KB
    __shared__ uint wsum[16];
    __shared__ uint2 sbuf[P1_CHUNK];      // 64 KB
    __shared__ ushort sbin[P1_CHUNK];     // 16 KB
    uint* hist = (uint*)delta;

    int t0 = blockIdx.x * P1_CHUNK;
    int m = T - t0;
    if (m <= 0) return;
    if (m > P1_CHUNK) m = P1_CHUNK;
    int tid = threadIdx.x;

    for (int i = tid; i < NBIN; i += blockDim.x) hist[i] = 0u;
    __syncthreads();

    for (int i = tid; i < m; i += blockDim.x)
        atomicAdd(&hist[((uint)tidx[t0 + i]) >> EPB_SHIFT], 1u);
    __syncthreads();

    // pair scan over 2048 bins with wave shuffles
    int b0 = 2 * tid, b1 = 2 * tid + 1;
    uint h0 = (b0 < NBIN) ? hist[b0] : 0u;
    uint h1 = (b1 < NBIN) ? hist[b1] : 0u;
    uint v = h0 + h1;
    uint lane = (uint)tid & 63u;
    uint wv = (uint)tid >> 6;
    uint sv = v;
#pragma unroll
    for (int o = 1; o < 64; o <<= 1) {
        uint u = __shfl_up(sv, o);
        if ((int)lane >= o) sv += u;
    }
    if (lane == 63u) wsum[wv] = sv;
    __syncthreads();
    if (tid == 0) {
        uint s = 0;
        for (int w = 0; w < 16; ++w) { uint x = wsum[w]; wsum[w] = s; s += x; }
    }
    __syncthreads();
    uint incl = sv + wsum[wv];
    uint exPair = incl - v;
    uint ex0 = exPair, ex1 = exPair + h0;
    __syncthreads();   // all hist reads done before delta overwrite
    if (b0 < NBIN) {
        lcur[b0] = ex0;
        uint gb = h0 ? atomicAdd(&gcount[b0 * GC_STRIDE], h0) : 0u;
        delta[b0] = (int)gb - (int)ex0;
    }
    if (b1 < NBIN) {
        lcur[b1] = ex1;
        uint gb = h1 ? atomicAdd(&gcount[b1 * GC_STRIDE], h1) : 0u;
        delta[b1] = (int)gb - (int)ex1;
    }
    __syncthreads();

    // pass B: build records, place sorted by bin (cursor starts at local base)
    for (int i = tid; i < m; i += blockDim.x) {
        int t = t0 + i;
        uint ij = (uint)tidx[t];
        uint ik = (uint)tidx[T + t];
        float ca = ang[t];
        uint te = tab[ik];
        uint bin = ij >> EPB_SHIFT;
        uint p = atomicAdd(&lcur[bin], 1u);
        uint cah = (uint)__half_as_ushort(__float2half_rn(ca));
        sbuf[p] = make_uint2((cah << 16) | (te >> 16),
                             ((ij & (EPB - 1u)) << 16) | (te & 0xFFFFu));
        sbin[p] = (ushort)bin;
    }
    __syncthreads();

    // pass C: coalesced writeout of sorted runs
    for (int i = tid; i < m; i += blockDim.x) {
        uint bin = sbin[i];
        uint2 rec = sbuf[i];
        int slot = i + delta[bin];     // = gbase + (i - localBase), >= 0
        if ((uint)slot < (uint)BCAP) {
            binbuf[(size_t)bin * BCAP + slot] = rec;
        } else {
            atomicOr(&gcount[bin * GC_STRIDE + 1], 1u);
            spill_rec(rec, (int)bin, gate16h, mid);
        }
    }
}

// ---------------- Pass 2: one bin per block; in-LDS sort + paired register accumulate ----------------
// 1024 threads = 2 per edge (even/odd record split): max-iteration imbalance halves,
// 2 blocks/CU = 32 waves (100% ceiling). LDS unchanged.
__global__ void __launch_bounds__(P2_THREADS) p2_sorted_kernel(
        const float* __restrict__ dist,
        const uint* __restrict__ gate16h, // [N,8]
        const uint* __restrict__ gcount,  // [NBIN*GC_STRIDE]
        const uint2* __restrict__ binbuf,
        const float* __restrict__ mid,    // [E,9] spill acc
        const float* __restrict__ attr,
        const float* __restrict__ Wm,
        const float* __restrict__ bm,
        const float* __restrict__ Wg,
        const float* __restrict__ bg,
        float* __restrict__ out,
        int E, int BCAP) {
    __shared__ uint2 srec[SCAP];          // 36 KB; aliased as pmid/umid after records consumed
    __shared__ uint cnt[EPB];             // 2 KB
    __shared__ uint off[EPB];             // 2 KB
    __shared__ uint wsum[8];
    __shared__ float sWm[576], sWg[576], sbm[64], sbg[64];
    float* umid = (float*)srec;           // [EPB*9] aliased (18 KB < 36 KB)

    int tid = threadIdx.x;
    for (int i = tid; i < 576; i += P2_THREADS) { sWm[i] = Wm[i]; sWg[i] = Wg[i]; }
    if (tid < 64) { sbm[tid] = bm[tid]; sbg[tid] = bg[tid]; }
    if (tid < EPB) cnt[tid] = 0;

    int bin = blockIdx.x;
    int ebase = bin << EPB_SHIFT;
    int ecnt = E - ebase; if (ecnt < 0) ecnt = 0; if (ecnt > EPB) ecnt = EPB;

    uint n = gcount[bin * GC_STRIDE];
    uint has_spill = gcount[bin * GC_STRIDE + 1];
    if (n > (uint)BCAP) n = (uint)BCAP;
    const uint2* rb = binbuf + (size_t)bin * BCAP;
    __syncthreads();

    // pass A: histogram (every record is ours)
    for (uint i = tid; i < n; i += P2_THREADS)
        atomicAdd(&cnt[(rb[i].y >> 16) & (EPB - 1u)], 1u);
    __syncthreads();
    // wave-shuffle scan over 512 entries (threads < EPB participate)
    if (tid < EPB) {
        uint myCnt = cnt[tid];
        uint lane = (uint)tid & 63u;
        uint wv = (uint)tid >> 6;
        uint sv = myCnt;
#pragma unroll
        for (int o = 1; o < 64; o <<= 1) {
            uint u = __shfl_up(sv, o);
            if ((int)lane >= o) sv += u;
        }
        if (lane == 63u) wsum[wv] = sv;
        __syncthreads();
        if (tid == 0) {
            uint s = 0;
            for (int w = 0; w < 8; ++w) { uint x = wsum[w]; wsum[w] = s; s += x; }
        }
        __syncthreads();
        off[tid] = sv + wsum[wv] - myCnt;   // exclusive base per edge
        cnt[tid] = 0;                       // scatter cursor
    } else {
        __syncthreads();
        __syncthreads();
    }
    __syncthreads();

    if (n <= (uint)SCAP) {
        // mode A: scatter into sorted LDS (all 1024 threads)
        for (uint i = tid; i < n; i += P2_THREADS) {
            uint2 r = rb[i];
            uint e = (r.y >> 16) & (EPB - 1u);
            uint p = off[e] + atomicAdd(&cnt[e], 1u);
            srec[p] = r;
        }
        __syncthreads();
        // paired accumulate: threads 2e, 2e+1 split edge e's records even/odd
        int e = tid >> 1;
        int half = tid & 1;
        uint baseE = off[e];
        uint cntE = cnt[e];       // cursor ended at count
        float acc[9];
#pragma unroll
        for (int d = 0; d < 9; ++d) acc[d] = 0.0f;
        for (uint j = (uint)half; j < cntE; j += 2) {
            float c[9];
            contrib9(srec[baseE + j], gate16h, c);
#pragma unroll
            for (int d = 0; d < 9; ++d) acc[d] += c[d];
        }
        __syncthreads();   // all srec reads done before aliasing writes
        // odd thread deposits partial; even thread combines
        if (half == 1) {
#pragma unroll
            for (int d = 0; d < 9; ++d) umid[e * 9 + d] = acc[d];
        }
        __syncthreads();
        if (half == 0 && e < ecnt) {
            int eg = ebase + e;
            float fc = fcut(dist[eg]);
#pragma unroll
            for (int d = 0; d < 9; ++d) acc[d] += umid[e * 9 + d];
            if (has_spill) {
                const float* mg = mid + (size_t)eg * 9;
#pragma unroll
                for (int d = 0; d < 9; ++d) acc[d] = fc * (acc[d] + mg[d]);
            } else {
#pragma unroll
                for (int d = 0; d < 9; ++d) acc[d] *= fc;
            }
#pragma unroll
            for (int d = 0; d < 9; ++d) umid[e * 9 + d] = acc[d];
        }
        __syncthreads();
    } else {
        // mode B (rare fat bin): atomic accumulate into umid region
        for (int i = tid; i < EPB * 9; i += P2_THREADS) umid[i] = 0.0f;
        __syncthreads();
        for (uint i = tid; i < n; i += P2_THREADS) {
            uint2 r = rb[i];
            uint e = (r.y >> 16) & (EPB - 1u);
            float c[9];
            contrib9(r, gate16h, c);
            float* d0 = &umid[e * 9];
#pragma unroll
            for (int d = 0; d < 9; ++d) atomicAdd(d0 + d, c[d]);
        }
        __syncthreads();
        if (tid < ecnt) {
            int eg = ebase + tid;
            float fc = fcut(dist[eg]);
            float* ls = &umid[tid * 9];
            if (has_spill) {
                const float* mg = mid + (size_t)eg * 9;
#pragma unroll
                for (int d = 0; d < 9; ++d) ls[d] = fc * (ls[d] + mg[d]);
            } else {
#pragma unroll
                for (int d = 0; d < 9; ++d) ls[d] *= fc;
            }
        }
        __syncthreads();
    }

    // GatedMLP epilogue: wave per edge, lane = feature (16 waves)
    int wid  = tid >> 6;
    int lane2 = tid & 63;
    for (int el = wid; el < ecnt; el += (P2_THREADS >> 6)) {
        int e = ebase + el;
        const float* ls = &umid[el * 9];
        float am = sbm[lane2], ag = sbg[lane2];
#pragma unroll
        for (int d = 0; d < 9; ++d) {
            float ud = ls[d];
            am += ud * sWm[d * 64 + lane2];
            ag += ud * sWg[d * 64 + lane2];
        }
        float hsw = am / (1.0f + __expf(-am));
        float gt  = 1.0f / (1.0f + __expf(-ag));
        size_t ofs = (size_t)e * 64 + lane2;
        out[ofs] = attr[ofs] + hsw * gt;
    }
}

// ---------------- Legacy fallback (round-1 path) ----------------
__global__ void triplet_kernel(const float* __restrict__ dist,
                               const float* __restrict__ ang,
                               const int* __restrict__ tidx,
                               const int* __restrict__ eidx,
                               const float* __restrict__ gate,
                               float* __restrict__ mid,
                               int T, int E) {
    int t = blockIdx.x * blockDim.x + threadIdx.x;
    if (t >= T) return;
    int ij = tidx[t];
    int ik = tidx[T + t];
    float ca  = ang[t];
    float rij = dist[ij];
    float rik = dist[ik];
    float frij = fcut(rij);
    int nk = eidx[E + ik];
    const float* g = gate + (size_t)nk * 9;
    float vr[9];
    radial9(rik, vr);
    float s0, s1, s2;
    legendre_s(ca, s0, s1, s2);
    s0 *= frij; s1 *= frij; s2 *= frij;
    float* dst = mid + (size_t)ij * 9;
    atomicAdd(dst + 0, vr[0] * s0 * g[0]);
    atomicAdd(dst + 1, vr[1] * s0 * g[1]);
    atomicAdd(dst + 2, vr[2] * s0 * g[2]);
    atomicAdd(dst + 3, vr[3] * s1 * g[3]);
    atomicAdd(dst + 4, vr[4] * s1 * g[4]);
    atomicAdd(dst + 5, vr[5] * s1 * g[5]);
    atomicAdd(dst + 6, vr[6] * s2 * g[6]);
    atomicAdd(dst + 7, vr[7] * s2 * g[7]);
    atomicAdd(dst + 8, vr[8] * s2 * g[8]);
}

__global__ void edge_kernel(const float* __restrict__ mid,
                            const float* __restrict__ attr,
                            const float* __restrict__ Wm, const float* __restrict__ bm,
                            const float* __restrict__ Wg, const float* __restrict__ bg,
                            float* __restrict__ out, int E) {
    __shared__ float sWm[9 * 64], sWg[9 * 64], sbm[64], sbg[64];
    for (int i = threadIdx.x; i < 576; i += blockDim.x) {
        sWm[i] = Wm[i];
        sWg[i] = Wg[i];
    }
    if (threadIdx.x < 64) {
        sbm[threadIdx.x] = bm[threadIdx.x];
        sbg[threadIdx.x] = bg[threadIdx.x];
    }
    __syncthreads();
    int wid  = threadIdx.x >> 6;
    int lane = threadIdx.x & 63;
    int e = blockIdx.x * (blockDim.x >> 6) + wid;
    if (e >= E) return;
    const float* u = mid + (size_t)e * 9;
    float am = sbm[lane], ag = sbg[lane];
#pragma unroll
    for (int d = 0; d < 9; ++d) {
        float ud = u[d];
        am += ud * sWm[d * 64 + lane];
        ag += ud * sWg[d * 64 + lane];
    }
    float h  = am / (1.0f + __expf(-am));
    float gt = 1.0f / (1.0f + __expf(-ag));
    size_t off = (size_t)e * 64 + lane;
    out[off] = attr[off] + h * gt;
}

extern "C" void kernel_launch(void* const* d_in, const int* in_sizes, int n_in,
                              void* d_out, int out_size, void* d_ws, size_t ws_size,
                              hipStream_t stream) {
    const float* dist = (const float*)d_in[0];
    const float* ang  = (const float*)d_in[1];
    const float* nf   = (const float*)d_in[2];
    const float* attr = (const float*)d_in[3];
    const float* W1   = (const float*)d_in[4];
    const float* b1   = (const float*)d_in[5];
    const float* Wm   = (const float*)d_in[6];
    const float* bm   = (const float*)d_in[7];
    const float* Wg   = (const float*)d_in[8];
    const float* bg   = (const float*)d_in[9];
    const int* tidx   = (const int*)d_in[10];
    const int* eidx   = (const int*)d_in[11];

    int E = in_sizes[0];
    int T = in_sizes[1];
    int N = in_sizes[2] / 64;

    int NBIN = (E + EPB - 1) >> EPB_SHIFT;
    int mean = T / (NBIN > 0 ? NBIN : 1);

    int bcap1 = ((mean + mean / 8 + 512) + 15) & ~15;
    int bcap2 = ((mean + mean / 32 + 256) + 15) & ~15;

    size_t o_gate  = 0;
    size_t o_tab   = o_gate + (size_t)N * 8;
    size_t o_mid   = o_tab + (size_t)E;
    size_t o_gcnt  = o_mid + (size_t)E * 9;
    size_t o_bb    = (o_gcnt + (size_t)NBIN * GC_STRIDE + 15) & ~(size_t)15;
    auto need = [&](int cap) { return (o_bb + (size_t)NBIN * cap * 2) * 4; };

    int BCAP = 0;
    if (ws_size >= need(bcap1)) BCAP = bcap1;
    else if (ws_size >= need(bcap2)) BCAP = bcap2;

    bool newpath = (E <= (1 << 20)) && (N <= 65535) && (NBIN <= NBIN_MAX)
                   && (NBIN <= 2 * P1_THREADS) && (BCAP > 0);

    float* wsf = (float*)d_ws;

    if (newpath) {
        uint*  gate16h = (uint*)(wsf + o_gate);
        uint*  tab     = (uint*)(wsf + o_tab);
        float* mid     = wsf + o_mid;
        uint*  gcount  = (uint*)(wsf + o_gcnt);
        uint2* binbuf  = (uint2*)(wsf + o_bb);

        hipMemsetAsync(gcount, 0, (size_t)NBIN * GC_STRIDE * sizeof(uint), stream);
        hipMemsetAsync(mid, 0, (size_t)E * 9 * sizeof(float), stream);
        node_gate_h16_kernel<<<(N + 255) / 256, 256, 0, stream>>>(nf, W1, b1, gate16h, N);
        edge_tab_kernel<<<(E + 255) / 256, 256, 0, stream>>>(dist, eidx, tab, E);

        int p1grid = (T + P1_CHUNK - 1) / P1_CHUNK;
        p1_sort_kernel<<<p1grid, P1_THREADS, 0, stream>>>(ang, tidx, tab, gcount, binbuf,
                                                          gate16h, mid, T, NBIN, BCAP);
        p2_sorted_kernel<<<NBIN, P2_THREADS, 0, stream>>>(dist, gate16h, gcount, binbuf, mid,
                                                          attr, Wm, bm, Wg, bg,
                                                          (float*)d_out, E, BCAP);
    } else {
        float* gate = wsf;
        float* mid = gate + (((size_t)N * 9 + 15) & ~(size_t)15);
        hipMemsetAsync(mid, 0, (size_t)E * 9 * sizeof(float), stream);
        node_gate_f32_kernel<<<(N + 255) / 256, 256, 0, stream>>>(nf, W1, b1, gate, N);
        triplet_kernel<<<(T + 255) / 256, 256, 0, stream>>>(dist, ang, tidx, eidx, gate, mid, T, E);
        edge_kernel<<<(E + 3) / 4, 256, 0, stream>>>(mid, attr, Wm, bm, Wg, bg, (float*)d_out, E);
    }
}

// Round 19
// 426.989 us; speedup vs baseline: 1.2436x; 1.0014x over previous
//
#include <hip/hip_runtime.h>
#include <hip/hip_fp16.h>
#include <math.h>

#define CUTOFF_INV 0.2f
#define EPB_SHIFT 9
#define EPB 512             // edges per bin == edges per p2 block
#define NBIN_MAX 2048
#define P1_CHUNK 8192
#define P1_THREADS 1024
#define P2_THREADS 1024     // 2 threads per edge
#define SCAP 4608           // LDS sorted-record capacity per bin (mean ~3906, ~11 sigma)
#define GC_STRIDE 16        // gcount padding; [..+1] = overflow flag
#define RT_N 513            // radial table nodes (every 8th f16 bit in [0x3800, 0x4800])
#define RT_BASE 0x3800

typedef unsigned int uint;
typedef unsigned short ushort;

__device__ __forceinline__ float fcut(float r) {
    float p = r * CUTOFF_INV;
    float p2 = p * p;
    float p3 = p2 * p;
    return 1.0f + p3 * (-10.0f + p * (15.0f - 6.0f * p));
}

__device__ __forceinline__ void legendre_s(float ca, float& s0, float& s1, float& s2) {
    s0 = 0.5641895835477563f;
    s1 = 0.9772050238058398f * ca;
    s2 = 1.2615662610100802f * (1.5f * ca * ca - 0.5f);
}

// divide-free radial: v[l*3+n] = j_l(z_{l,n} * rik / cutoff) * fc(rik)
__device__ __forceinline__ void radial9(float rik, float* v) {
    float rr = rik * CUTOFF_INV;
    float inv = __builtin_amdgcn_rcpf(rr);
    inv = inv * (2.0f - rr * inv);
    float fcik = fcut(rik);

    const float Z0[3]  = {3.14159265358979324f, 6.28318530717958648f, 9.42477796076937972f};
    const float IZ0[3] = {1.0f / 3.14159265358979324f, 1.0f / 6.28318530717958648f, 1.0f / 9.42477796076937972f};
    const float Z1[3]  = {4.49340945790806150f, 7.72525183693865170f, 10.9041216594298970f};
    const float IZ1[3] = {1.0f / 4.49340945790806150f, 1.0f / 7.72525183693865170f, 1.0f / 10.9041216594298970f};
    const float Z2[3]  = {5.76345919689554900f, 9.09501133047736000f, 12.3229409705673230f};
    const float IZ2[3] = {1.0f / 5.76345919689554900f, 1.0f / 9.09501133047736000f, 1.0f / 12.3229409705673230f};

#pragma unroll
    for (int n = 0; n < 3; ++n) {
        float x = Z0[n] * rr;
        float invx = IZ0[n] * inv;
        v[n] = __sinf(x) * invx * fcik;
    }
#pragma unroll
    for (int n = 0; n < 3; ++n) {
        float x = Z1[n] * rr;
        float invx = IZ1[n] * inv;
        float s, c;
        __sincosf(x, &s, &c);
        v[3 + n] = (s * invx - c) * invx * fcik;
    }
#pragma unroll
    for (int n = 0; n < 3; ++n) {
        float x = Z2[n] * rr;
        float invx = IZ2[n] * inv;
        float s, c;
        __sincosf(x, &s, &c);
        float sx = s * invx;
        float j1 = (sx - c) * invx;
        v[6 + n] = (3.0f * invx * j1 - sx) * fcik;
    }
}

__device__ __forceinline__ float h2f(uint w) { return __half2float(__ushort_as_half((ushort)w)); }

// full per-record contribution c[9] (exact path; used by spill & mode B)
__device__ __forceinline__ void contrib9(uint2 r, const uint* __restrict__ gate16h, float* c) {
    uint nk = r.y & 0xFFFFu;
    const uint* G = gate16h + ((size_t)nk << 3);
    uint4 q = *(const uint4*)G;
    uint q8 = G[4];
    float ca  = h2f(r.x >> 16);
    float rik = h2f(r.x & 0xFFFFu);
    float vr[9];
    radial9(rik, vr);
    float s0, s1, s2;
    legendre_s(ca, s0, s1, s2);
    c[0] = vr[0] * h2f(q.x & 0xFFFFu) * s0;
    c[1] = vr[1] * h2f(q.x >> 16) * s0;
    c[2] = vr[2] * h2f(q.y & 0xFFFFu) * s0;
    c[3] = vr[3] * h2f(q.y >> 16) * s1;
    c[4] = vr[4] * h2f(q.z & 0xFFFFu) * s1;
    c[5] = vr[5] * h2f(q.z >> 16) * s1;
    c[6] = vr[6] * h2f(q.w & 0xFFFFu) * s2;
    c[7] = vr[7] * h2f(q.w >> 16) * s2;
    c[8] = vr[8] * h2f(q8 & 0xFFFFu) * s2;
}

// ---------------- radial node table: radTabS[i][8 uints] = 9 f16 of radial9(h2f(RT_BASE+8i)) ----------------
__global__ void radtabS_kernel(uint* __restrict__ radTabS) {
    int t = blockIdx.x * blockDim.x + threadIdx.x;
    if (t >= RT_N) return;
    float rik = h2f((uint)(RT_BASE + 8 * t));
    float v[9];
    radial9(rik, v);
    uint h[9];
#pragma unroll
    for (int d = 0; d < 9; ++d) h[d] = (uint)__half_as_ushort(__float2half_rn(v[d]));
    uint* o = radTabS + ((size_t)t << 3);
    o[0] = h[0] | (h[1] << 16);
    o[1] = h[2] | (h[3] << 16);
    o[2] = h[4] | (h[5] << 16);
    o[3] = h[6] | (h[7] << 16);
    o[4] = h[8];
    o[5] = 0u; o[6] = 0u; o[7] = 0u;
}

// ---------------- Stage 1: node gate -> packed f16 rows [N][8 uints] ----------------
__global__ void node_gate_h16_kernel(const float* __restrict__ nf,
                                     const float* __restrict__ W1,
                                     const float* __restrict__ b1,
                                     uint* __restrict__ gate16h, int N) {
    __shared__ float sW[64 * 9];
    __shared__ float sb[9];
    for (int i = threadIdx.x; i < 576; i += blockDim.x) sW[i] = W1[i];
    if (threadIdx.x < 9) sb[threadIdx.x] = b1[threadIdx.x];
    __syncthreads();
    int t = blockIdx.x * blockDim.x + threadIdx.x;
    if (t >= N) return;
    float acc[9];
#pragma unroll
    for (int d = 0; d < 9; ++d) acc[d] = sb[d];
    const float* row = nf + (size_t)t * 64;
#pragma unroll
    for (int f = 0; f < 64; ++f) {
        float x = row[f];
#pragma unroll
        for (int d = 0; d < 9; ++d) acc[d] += x * sW[f * 9 + d];
    }
    float g[9];
#pragma unroll
    for (int d = 0; d < 9; ++d) g[d] = 1.0f / (1.0f + __expf(-acc[d]));
    uint* o = gate16h + ((size_t)t << 3);
#pragma unroll
    for (int d = 0; d < 4; ++d) {
        uint lo = (uint)__half_as_ushort(__float2half_rn(g[2 * d]));
        uint hi = (uint)__half_as_ushort(__float2half_rn(g[2 * d + 1]));
        o[d] = lo | (hi << 16);
    }
    o[4] = (uint)__half_as_ushort(__float2half_rn(g[8]));
    o[5] = 0u; o[6] = 0u; o[7] = 0u;
}

// ---------------- Stage 1 (legacy): f32 gate [N,9] ----------------
__global__ void node_gate_f32_kernel(const float* __restrict__ nf,
                                     const float* __restrict__ W1,
                                     const float* __restrict__ b1,
                                     float* __restrict__ gate, int N) {
    __shared__ float sW[64 * 9];
    __shared__ float sb[9];
    for (int i = threadIdx.x; i < 576; i += blockDim.x) sW[i] = W1[i];
    if (threadIdx.x < 9) sb[threadIdx.x] = b1[threadIdx.x];
    __syncthreads();
    int t = blockIdx.x * blockDim.x + threadIdx.x;
    if (t >= N) return;
    float acc[9];
#pragma unroll
    for (int d = 0; d < 9; ++d) acc[d] = sb[d];
    const float* row = nf + (size_t)t * 64;
#pragma unroll
    for (int f = 0; f < 64; ++f) {
        float x = row[f];
#pragma unroll
        for (int d = 0; d < 9; ++d) acc[d] += x * sW[f * 9 + d];
    }
#pragma unroll
    for (int d = 0; d < 9; ++d)
        gate[(size_t)t * 9 + d] = 1.0f / (1.0f + __expf(-acc[d]));
}

// ---------------- Stage 2a: tab[e] = (f16(rik) << 16) | nk ----------------
__global__ void edge_tab_kernel(const float* __restrict__ dist,
                                const int* __restrict__ eidx,
                                uint* __restrict__ tab, int E) {
    int e = blockIdx.x * blockDim.x + threadIdx.x;
    if (e >= E) return;
    uint rh = (uint)__half_as_ushort(__float2half_rn(dist[e]));
    tab[e] = (rh << 16) | (uint)eidx[E + e];
}

// overflow fallback: accumulate one record straight into global mid
__device__ __forceinline__ void spill_rec(uint2 rec, int bin,
                                          const uint* __restrict__ gate16h,
                                          float* __restrict__ mid) {
    float c[9];
    contrib9(rec, gate16h, c);
    uint ijl = (rec.y >> 16) & (EPB - 1u);
    float* dst = mid + ((size_t)bin * EPB + ijl) * 9;
#pragma unroll
    for (int d = 0; d < 9; ++d) atomicAdd(dst + d, c[d]);
}

// ---------------- Pass 1: block-local counting sort -> 2048 native bins ----------------
__global__ void __launch_bounds__(P1_THREADS) p1_sort_kernel(
        const float* __restrict__ ang,
        const int* __restrict__ tidx, // [2,T]
        const uint* __restrict__ tab, // [E]
        uint* __restrict__ gcount,    // [NBIN*GC_STRIDE]
        uint2* __restrict__ binbuf,   // [NBIN*BCAP]
        const uint* __restrict__ gate16h,
        float* __restrict__ mid,
        int T, int NBIN, int BCAP) {
    __shared__ int  delta[NBIN_MAX];      // 8 KB; first used as hist
    __shared__ uint lcur[NBIN_MAX];       // 8 KB
    __shared__ uint wsum[16];
    __shared__ uint2 sbuf[P1_CHUNK];      // 64 KB
    __shared__ ushort sbin[P1_CHUNK];     // 16 KB
    uint* hist = (uint*)delta;

    int t0 = blockIdx.x * P1_CHUNK;
    int m = T - t0;
    if (m <= 0) return;
    if (m > P1_CHUNK) m = P1_CHUNK;
    int tid = threadIdx.x;

    for (int i = tid; i < NBIN; i += blockDim.x) hist[i] = 0u;
    __syncthreads();

    for (int i = tid; i < m; i += blockDim.x)
        atomicAdd(&hist[((uint)tidx[t0 + i]) >> EPB_SHIFT], 1u);
    __syncthreads();

    // pair scan over 2048 bins with wave shuffles
    int b0 = 2 * tid, b1 = 2 * tid + 1;
    uint h0 = (b0 < NBIN) ? hist[b0] : 0u;
    uint h1 = (b1 < NBIN) ? hist[b1] : 0u;
    uint v = h0 + h1;
    uint lane = (uint)tid & 63u;
    uint wv = (uint)tid >> 6;
    uint sv = v;
#pragma unroll
    for (int o = 1; o < 64; o <<= 1) {
        uint u = __shfl_up(sv, o);
        if ((int)lane >= o) sv += u;
    }
    if (lane == 63u) wsum[wv] = sv;
    __syncthreads();
    if (tid == 0) {
        uint s = 0;
        for (int w = 0; w < 16; ++w) { uint x = wsum[w]; wsum[w] = s; s += x; }
    }
    __syncthreads();
    uint incl = sv + wsum[wv];
    uint exPair = incl - v;
    uint ex0 = exPair, ex1 = exPair + h0;
    __syncthreads();   // all hist reads done before delta overwrite
    if (b0 < NBIN) {
        lcur[b0] = ex0;
        uint gb = h0 ? atomicAdd(&gcount[b0 * GC_STRIDE], h0) : 0u;
        delta[b0] = (int)gb - (int)ex0;
    }
    if (b1 < NBIN) {
        lcur[b1] = ex1;
        uint gb = h1 ? atomicAdd(&gcount[b1 * GC_STRIDE], h1) : 0u;
        delta[b1] = (int)gb - (int)ex1;
    }
    __syncthreads();

    // pass B: build records, place sorted by bin (cursor starts at local base)
    for (int i = tid; i < m; i += blockDim.x) {
        int t = t0 + i;
        uint ij = (uint)tidx[t];
        uint ik = (uint)tidx[T + t];
        float ca = ang[t];
        uint te = tab[ik];
        uint bin = ij >> EPB_SHIFT;
        uint p = atomicAdd(&lcur[bin], 1u);
        uint cah = (uint)__half_as_ushort(__float2half_rn(ca));
        sbuf[p] = make_uint2((cah << 16) | (te >> 16),
                             ((ij & (EPB - 1u)) << 16) | (te & 0xFFFFu));
        sbin[p] = (ushort)bin;
    }
    __syncthreads();

    // pass C: coalesced writeout of sorted runs
    for (int i = tid; i < m; i += blockDim.x) {
        uint bin = sbin[i];
        uint2 rec = sbuf[i];
        int slot = i + delta[bin];     // = gbase + (i - localBase), >= 0
        if ((uint)slot < (uint)BCAP) {
            binbuf[(size_t)bin * BCAP + slot] = rec;
        } else {
            atomicOr(&gcount[bin * GC_STRIDE + 1], 1u);
            spill_rec(rec, (int)bin, gate16h, mid);
        }
    }
}

// ---------------- Pass 2: one bin per block; in-LDS sort + LDS-table accumulate ----------------
// Radial basis via 513-node LDS table + bit-space lerp: no transcendentals in the hot loop.
__global__ void __launch_bounds__(P2_THREADS) p2_sorted_kernel(
        const float* __restrict__ dist,
        const uint* __restrict__ radTabS, // [RT_N,8]
        const uint* __restrict__ gate16h, // [N,8]
        const uint* __restrict__ gcount,  // [NBIN*GC_STRIDE]
        const uint2* __restrict__ binbuf,
        const float* __restrict__ mid,    // [E,9] spill acc
        const float* __restrict__ attr,
        const float* __restrict__ Wm,
        const float* __restrict__ bm,
        const float* __restrict__ Wg,
        const float* __restrict__ bg,
        float* __restrict__ out,
        int E, int BCAP) {
    __shared__ uint2 srec[SCAP];          // 36 KB; aliased as umid after records consumed
    __shared__ uint ltab[RT_N * 8];       // 16.4 KB radial node table
    __shared__ uint cnt[EPB];             // 2 KB
    __shared__ uint off[EPB];             // 2 KB
    __shared__ uint wsum[8];
    __shared__ float sWm[576], sWg[576], sbm[64], sbg[64];
    float* umid = (float*)srec;           // [EPB*9] aliased (18 KB < 36 KB)

    int tid = threadIdx.x;
    for (int i = tid; i < 576; i += P2_THREADS) { sWm[i] = Wm[i]; sWg[i] = Wg[i]; }
    for (int i = tid; i < RT_N * 8; i += P2_THREADS) ltab[i] = radTabS[i];
    if (tid < 64) { sbm[tid] = bm[tid]; sbg[tid] = bg[tid]; }
    if (tid < EPB) cnt[tid] = 0;

    int bin = blockIdx.x;
    int ebase = bin << EPB_SHIFT;
    int ecnt = E - ebase; if (ecnt < 0) ecnt = 0; if (ecnt > EPB) ecnt = EPB;

    uint n = gcount[bin * GC_STRIDE];
    uint has_spill = gcount[bin * GC_STRIDE + 1];
    if (n > (uint)BCAP) n = (uint)BCAP;
    const uint2* rb = binbuf + (size_t)bin * BCAP;
    __syncthreads();

    // pass A: histogram (every record is ours)
    for (uint i = tid; i < n; i += P2_THREADS)
        atomicAdd(&cnt[(rb[i].y >> 16) & (EPB - 1u)], 1u);
    __syncthreads();
    // wave-shuffle scan over 512 entries (threads < EPB participate)
    if (tid < EPB) {
        uint myCnt = cnt[tid];
        uint lane = (uint)tid & 63u;
        uint wv = (uint)tid >> 6;
        uint sv = myCnt;
#pragma unroll
        for (int o = 1; o < 64; o <<= 1) {
            uint u = __shfl_up(sv, o);
            if ((int)lane >= o) sv += u;
        }
        if (lane == 63u) wsum[wv] = sv;
        __syncthreads();
        if (tid == 0) {
            uint s = 0;
            for (int w = 0; w < 8; ++w) { uint x = wsum[w]; wsum[w] = s; s += x; }
        }
        __syncthreads();
        off[tid] = sv + wsum[wv] - myCnt;   // exclusive base per edge
        cnt[tid] = 0;                       // scatter cursor
    } else {
        __syncthreads();
        __syncthreads();
    }
    __syncthreads();

    if (n <= (uint)SCAP) {
        // mode A: scatter into sorted LDS (all 1024 threads)
        for (uint i = tid; i < n; i += P2_THREADS) {
            uint2 r = rb[i];
            uint e = (r.y >> 16) & (EPB - 1u);
            uint p = off[e] + atomicAdd(&cnt[e], 1u);
            srec[p] = r;
        }
        __syncthreads();
        // paired accumulate: threads 2e, 2e+1 split edge e's records even/odd
        int e = tid >> 1;
        int half = tid & 1;
        uint baseE = off[e];
        uint cntE = cnt[e];       // cursor ended at count
        float acc[9];
#pragma unroll
        for (int d = 0; d < 9; ++d) acc[d] = 0.0f;
        for (uint j = (uint)half; j < cntE; j += 2) {
            uint2 r = srec[baseE + j];
            // gate row (global, L2-hot)
            const uint* G = gate16h + ((size_t)(r.y & 0xFFFFu) << 3);
            uint4 qg = *(const uint4*)G;
            uint qg8 = G[4];
            // radial via LDS table + bit-space lerp
            int u = (int)(r.x & 0xFFFFu) - RT_BASE;
            u = min(max(u, 0), 4095);
            int i0 = u >> 3;
            float f = (float)(u & 7) * 0.125f;
            const uint* R0 = &ltab[i0 << 3];
            const uint* R1 = &ltab[(i0 + 1) << 3];
            uint4 ra = *(const uint4*)R0; uint ra8 = R0[4];
            uint4 rbv = *(const uint4*)R1; uint rb8 = R1[4];
            float ca = h2f(r.x >> 16);
            float s0, s1, s2;
            legendre_s(ca, s0, s1, s2);
#define LERP1(lo_, hi_) (h2f(lo_) + f * (h2f(hi_) - h2f(lo_)))
            acc[0] += LERP1(ra.x & 0xFFFFu, rbv.x & 0xFFFFu) * h2f(qg.x & 0xFFFFu) * s0;
            acc[1] += LERP1(ra.x >> 16,     rbv.x >> 16)     * h2f(qg.x >> 16)     * s0;
            acc[2] += LERP1(ra.y & 0xFFFFu, rbv.y & 0xFFFFu) * h2f(qg.y & 0xFFFFu) * s0;
            acc[3] += LERP1(ra.y >> 16,     rbv.y >> 16)     * h2f(qg.y >> 16)     * s1;
            acc[4] += LERP1(ra.z & 0xFFFFu, rbv.z & 0xFFFFu) * h2f(qg.z & 0xFFFFu) * s1;
            acc[5] += LERP1(ra.z >> 16,     rbv.z >> 16)     * h2f(qg.z >> 16)     * s1;
            acc[6] += LERP1(ra.w & 0xFFFFu, rbv.w & 0xFFFFu) * h2f(qg.w & 0xFFFFu) * s2;
            acc[7] += LERP1(ra.w >> 16,     rbv.w >> 16)     * h2f(qg.w >> 16)     * s2;
            acc[8] += LERP1(ra8 & 0xFFFFu,  rb8 & 0xFFFFu)   * h2f(qg8 & 0xFFFFu)  * s2;
#undef LERP1
        }
        __syncthreads();   // all srec reads done before aliasing writes
        // odd thread deposits partial; even thread combines
        if (half == 1) {
#pragma unroll
            for (int d = 0; d < 9; ++d) umid[e * 9 + d] = acc[d];
        }
        __syncthreads();
        if (half == 0 && e < ecnt) {
            int eg = ebase + e;
            float fc = fcut(dist[eg]);
#pragma unroll
            for (int d = 0; d < 9; ++d) acc[d] += umid[e * 9 + d];
            if (has_spill) {
                const float* mg = mid + (size_t)eg * 9;
#pragma unroll
                for (int d = 0; d < 9; ++d) acc[d] = fc * (acc[d] + mg[d]);
            } else {
#pragma unroll
                for (int d = 0; d < 9; ++d) acc[d] *= fc;
            }
#pragma unroll
            for (int d = 0; d < 9; ++d) umid[e * 9 + d] = acc[d];
        }
        __syncthreads();
    } else {
        // mode B (rare fat bin): atomic accumulate into umid region (exact math)
        for (int i = tid; i < EPB * 9; i += P2_THREADS) umid[i] = 0.0f;
        __syncthreads();
        for (uint i = tid; i < n; i += P2_THREADS) {
            uint2 r = rb[i];
            uint e = (r.y >> 16) & (EPB - 1u);
            float c[9];
            contrib9(r, gate16h, c);
            float* d0 = &umid[e * 9];
#pragma unroll
            for (int d = 0; d < 9; ++d) atomicAdd(d0 + d, c[d]);
        }
        __syncthreads();
        if (tid < ecnt) {
            int eg = ebase + tid;
            float fc = fcut(dist[eg]);
            float* ls = &umid[tid * 9];
            if (has_spill) {
                const float* mg = mid + (size_t)eg * 9;
#pragma unroll
                for (int d = 0; d < 9; ++d) ls[d] = fc * (ls[d] + mg[d]);
            } else {
#pragma unroll
                for (int d = 0; d < 9; ++d) ls[d] *= fc;
            }
        }
        __syncthreads();
    }

    // GatedMLP epilogue: wave per edge, lane = feature (16 waves)
    int wid  = tid >> 6;
    int lane2 = tid & 63;
    for (int el = wid; el < ecnt; el += (P2_THREADS >> 6)) {
        int e = ebase + el;
        const float* ls = &umid[el * 9];
        float am = sbm[lane2], ag = sbg[lane2];
#pragma unroll
        for (int d = 0; d < 9; ++d) {
            float ud = ls[d];
            am += ud * sWm[d * 64 + lane2];
            ag += ud * sWg[d * 64 + lane2];
        }
        float hsw = am / (1.0f + __expf(-am));
        float gt  = 1.0f / (1.0f + __expf(-ag));
        size_t ofs = (size_t)e * 64 + lane2;
        out[ofs] = attr[ofs] + hsw * gt;
    }
}

// ---------------- Legacy fallback (round-1 path) ----------------
__global__ void triplet_kernel(const float* __restrict__ dist,
                               const float* __restrict__ ang,
                               const int* __restrict__ tidx,
                               const int* __restrict__ eidx,
                               const float* __restrict__ gate,
                               float* __restrict__ mid,
                               int T, int E) {
    int t = blockIdx.x * blockDim.x + threadIdx.x;
    if (t >= T) return;
    int ij = tidx[t];
    int ik = tidx[T + t];
    float ca  = ang[t];
    float rij = dist[ij];
    float rik = dist[ik];
    float frij = fcut(rij);
    int nk = eidx[E + ik];
    const float* g = gate + (size_t)nk * 9;
    float vr[9];
    radial9(rik, vr);
    float s0, s1, s2;
    legendre_s(ca, s0, s1, s2);
    s0 *= frij; s1 *= frij; s2 *= frij;
    float* dst = mid + (size_t)ij * 9;
    atomicAdd(dst + 0, vr[0] * s0 * g[0]);
    atomicAdd(dst + 1, vr[1] * s0 * g[1]);
    atomicAdd(dst + 2, vr[2] * s0 * g[2]);
    atomicAdd(dst + 3, vr[3] * s1 * g[3]);
    atomicAdd(dst + 4, vr[4] * s1 * g[4]);
    atomicAdd(dst + 5, vr[5] * s1 * g[5]);
    atomicAdd(dst + 6, vr[6] * s2 * g[6]);
    atomicAdd(dst + 7, vr[7] * s2 * g[7]);
    atomicAdd(dst + 8, vr[8] * s2 * g[8]);
}

__global__ void edge_kernel(const float* __restrict__ mid,
                            const float* __restrict__ attr,
                            const float* __restrict__ Wm, const float* __restrict__ bm,
                            const float* __restrict__ Wg, const float* __restrict__ bg,
                            float* __restrict__ out, int E) {
    __shared__ float sWm[9 * 64], sWg[9 * 64], sbm[64], sbg[64];
    for (int i = threadIdx.x; i < 576; i += blockDim.x) {
        sWm[i] = Wm[i];
        sWg[i] = Wg[i];
    }
    if (threadIdx.x < 64) {
        sbm[threadIdx.x] = bm[threadIdx.x];
        sbg[threadIdx.x] = bg[threadIdx.x];
    }
    __syncthreads();
    int wid  = threadIdx.x >> 6;
    int lane = threadIdx.x & 63;
    int e = blockIdx.x * (blockDim.x >> 6) + wid;
    if (e >= E) return;
    const float* u = mid + (size_t)e * 9;
    float am = sbm[lane], ag = sbg[lane];
#pragma unroll
    for (int d = 0; d < 9; ++d) {
        float ud = u[d];
        am += ud * sWm[d * 64 + lane];
        ag += ud * sWg[d * 64 + lane];
    }
    float h  = am / (1.0f + __expf(-am));
    float gt = 1.0f / (1.0f + __expf(-ag));
    size_t off = (size_t)e * 64 + lane;
    out[off] = attr[off] + h * gt;
}

extern "C" void kernel_launch(void* const* d_in, const int* in_sizes, int n_in,
                              void* d_out, int out_size, void* d_ws, size_t ws_size,
                              hipStream_t stream) {
    const float* dist = (const float*)d_in[0];
    const float* ang  = (const float*)d_in[1];
    const float* nf   = (const float*)d_in[2];
    const float* attr = (const float*)d_in[3];
    const float* W1   = (const float*)d_in[4];
    const float* b1   = (const float*)d_in[5];
    const float* Wm   = (const float*)d_in[6];
    const float* bm   = (const float*)d_in[7];
    const float* Wg   = (const float*)d_in[8];
    const float* bg   = (const float*)d_in[9];
    const int* tidx   = (const int*)d_in[10];
    const int* eidx   = (const int*)d_in[11];

    int E = in_sizes[0];
    int T = in_sizes[1];
    int N = in_sizes[2] / 64;

    int NBIN = (E + EPB - 1) >> EPB_SHIFT;
    int mean = T / (NBIN > 0 ? NBIN : 1);

    int bcap1 = ((mean + mean / 8 + 512) + 15) & ~15;
    int bcap2 = ((mean + mean / 32 + 256) + 15) & ~15;

    size_t o_gate  = 0;
    size_t o_rt    = o_gate + (size_t)N * 8;
    size_t o_tab   = o_rt + (size_t)RT_N * 8;
    size_t o_mid   = o_tab + (size_t)E;
    size_t o_gcnt  = o_mid + (size_t)E * 9;
    size_t o_bb    = (o_gcnt + (size_t)NBIN * GC_STRIDE + 15) & ~(size_t)15;
    auto need = [&](int cap) { return (o_bb + (size_t)NBIN * cap * 2) * 4; };

    int BCAP = 0;
    if (ws_size >= need(bcap1)) BCAP = bcap1;
    else if (ws_size >= need(bcap2)) BCAP = bcap2;

    bool newpath = (E <= (1 << 20)) && (N <= 65535) && (NBIN <= NBIN_MAX)
                   && (NBIN <= 2 * P1_THREADS) && (BCAP > 0);

    float* wsf = (float*)d_ws;

    if (newpath) {
        uint*  gate16h = (uint*)(wsf + o_gate);
        uint*  radTabS = (uint*)(wsf + o_rt);
        uint*  tab     = (uint*)(wsf + o_tab);
        float* mid     = wsf + o_mid;
        uint*  gcount  = (uint*)(wsf + o_gcnt);
        uint2* binbuf  = (uint2*)(wsf + o_bb);

        hipMemsetAsync(gcount, 0, (size_t)NBIN * GC_STRIDE * sizeof(uint), stream);
        hipMemsetAsync(mid, 0, (size_t)E * 9 * sizeof(float), stream);
        node_gate_h16_kernel<<<(N + 255) / 256, 256, 0, stream>>>(nf, W1, b1, gate16h, N);
        radtabS_kernel<<<(RT_N + 255) / 256, 256, 0, stream>>>(radTabS);
        edge_tab_kernel<<<(E + 255) / 256, 256, 0, stream>>>(dist, eidx, tab, E);

        int p1grid = (T + P1_CHUNK - 1) / P1_CHUNK;
        p1_sort_kernel<<<p1grid, P1_THREADS, 0, stream>>>(ang, tidx, tab, gcount, binbuf,
                                                          gate16h, mid, T, NBIN, BCAP);
        p2_sorted_kernel<<<NBIN, P2_THREADS, 0, stream>>>(dist, radTabS, gate16h, gcount,
                                                          binbuf, mid,
                                                          attr, Wm, bm, Wg, bg,
                                                          (float*)d_out, E, BCAP);
    } else {
        float* gate = wsf;
        float* mid = gate + (((size_t)N * 9 + 15) & ~(size_t)15);
        hipMemsetAsync(mid, 0, (size_t)E * 9 * sizeof(float), stream);
        node_gate_f32_kernel<<<(N + 255) / 256, 256, 0, stream>>>(nf, W1, b1, gate, N);
        triplet_kernel<<<(T + 255) / 256, 256, 0, stream>>>(dist, ang, tidx, eidx, gate, mid, T, E);
        edge_kernel<<<(E + 3) / 4, 256, 0, stream>>>(mid, attr, Wm, bm, Wg, bg, (float*)d_out, E);
    }
}